// Round 1
// baseline (3371.675 us; speedup 1.0000x reference)
//
#include <hip/hip_runtime.h>
#include <cstddef>

#define BN 2
#define NN 20000
#define NE 400000
#define HH 128

#define TE 64          // edges/nodes per block (M tile)
#define TK 32          // K tile
#define ASTRIDE 36     // padded LDS stride for A tile (16B-aligned, bank-friendly)
#define YSTRIDE 132    // padded LDS stride for activation tile

static_assert(NE % TE == 0, "edge grid must be exact");

// ---------------------------------------------------------------------------
// Edge kernel: per 64-edge tile, per batch:
//   e = [h[row], h[col], radial] (257)
//   y1 = relu(e @ w1 + b1)            K=257
//   feat = relu(y1 @ w2 + b2)         K=128
//   g1 = relu(feat @ cw1 + cb1)       K=128
//   gate = g1 @ cw2                   K=128 -> scalar
//   atomic: agg[b,row,:] += feat ; aggt[b,row,:] += coord_diff*gate ; cnt[row]+=1 (b==0)
// ---------------------------------------------------------------------------
__global__ __launch_bounds__(256, 2)
void edge_kernel(const float* __restrict__ h, const float* __restrict__ coord,
                 const int* __restrict__ eidx,
                 const float* __restrict__ w1, const float* __restrict__ b1,
                 const float* __restrict__ w2, const float* __restrict__ b2,
                 const float* __restrict__ cw1, const float* __restrict__ cb1,
                 const float* __restrict__ cw2,
                 float* __restrict__ agg, float* __restrict__ aggt,
                 float* __restrict__ cnt)
{
    __shared__ float As[TE][ASTRIDE];   // A k-tile (64 x 32)
    __shared__ float Ws[TK][HH];        // W k-tile (32 x 128)
    __shared__ float Y[TE][YSTRIDE];    // activation tile (64 x 128)
    __shared__ float CD[TE][3];
    __shared__ float Rad[TE];
    __shared__ int   Rw[TE];

    const int t  = threadIdx.x;
    const int tx = t & 15;      // j-group: outputs tx*8 .. tx*8+7
    const int ty = t >> 4;      // edge-group: edges ty*4 .. ty*4+3
    const int b  = blockIdx.y;
    const int e0 = blockIdx.x * TE;

    // staging assignment: thread handles edge (t>>2), k-subrange ((t&3)*8)
    const int se = t >> 2;
    const int sq = t & 3;
    const int srow = eidx[e0 + se];
    const int scol = eidx[NE + e0 + se];

    if (t < TE) {
        const int r = eidx[e0 + t];
        const int c = eidx[NE + e0 + t];
        Rw[t] = r;
        const float* cr = coord + ((size_t)b * NN + r) * 3;
        const float* cc = coord + ((size_t)b * NN + c) * 3;
        const float d0 = cr[0] - cc[0];
        const float d1 = cr[1] - cc[1];
        const float d2 = cr[2] - cc[2];
        CD[t][0] = d0; CD[t][1] = d1; CD[t][2] = d2;
        Rad[t] = d0 * d0 + d1 * d1 + d2 * d2;
        if (b == 0) atomicAdd(&cnt[r], 1.0f);
    }

    float acc[4][8];
    #pragma unroll
    for (int i = 0; i < 4; ++i)
        #pragma unroll
        for (int j = 0; j < 8; ++j) acc[i][j] = 0.0f;

    const int e_my = ty * 4;
    const int j_my = tx * 8;

    // ---------------- layer 1: K = 256 (+ radial row 256 in epilogue) -------
    for (int kt = 0; kt < 8; ++kt) {
        __syncthreads();  // WAR: previous tile's readers done
        {   // stage A: gathered h rows
            const int idx  = (kt < 4) ? srow : scol;
            const int koff = kt * TK - ((kt < 4) ? 0 : 128);
            const float* src = h + ((size_t)b * NN + idx) * HH + koff + sq * 8;
            *(float4*)&As[se][sq * 8]     = *(const float4*)src;
            *(float4*)&As[se][sq * 8 + 4] = *(const float4*)(src + 4);
        }
        {   // stage W tile: 32x128 floats
            const float4* wsrc = (const float4*)(w1 + (size_t)kt * TK * HH);
            float4* wdst = (float4*)&Ws[0][0];
            #pragma unroll
            for (int i = 0; i < 4; ++i) wdst[t + i * 256] = wsrc[t + i * 256];
        }
        __syncthreads();
        #pragma unroll 4
        for (int k = 0; k < TK; ++k) {
            const float a0 = As[e_my + 0][k];
            const float a1 = As[e_my + 1][k];
            const float a2 = As[e_my + 2][k];
            const float a3 = As[e_my + 3][k];
            const float4 wA = *(const float4*)&Ws[k][j_my];
            const float4 wB = *(const float4*)&Ws[k][j_my + 4];
            const float wv[8] = {wA.x, wA.y, wA.z, wA.w, wB.x, wB.y, wB.z, wB.w};
            #pragma unroll
            for (int j = 0; j < 8; ++j) {
                acc[0][j] += a0 * wv[j];
                acc[1][j] += a1 * wv[j];
                acc[2][j] += a2 * wv[j];
                acc[3][j] += a3 * wv[j];
            }
        }
    }

    // layer-1 epilogue: radial term + bias + relu -> Y
    {
        const float* w1r = w1 + 256 * HH;
        const float4 wA = *(const float4*)&w1r[j_my];
        const float4 wB = *(const float4*)&w1r[j_my + 4];
        const float4 bA = *(const float4*)&b1[j_my];
        const float4 bB = *(const float4*)&b1[j_my + 4];
        const float wv[8] = {wA.x, wA.y, wA.z, wA.w, wB.x, wB.y, wB.z, wB.w};
        const float bv[8] = {bA.x, bA.y, bA.z, bA.w, bB.x, bB.y, bB.z, bB.w};
        #pragma unroll
        for (int i = 0; i < 4; ++i) {
            const float r = Rad[e_my + i];
            float4 o0, o1;
            float vv[8];
            #pragma unroll
            for (int j = 0; j < 8; ++j) {
                vv[j] = fmaxf(acc[i][j] + r * wv[j] + bv[j], 0.0f);
                acc[i][j] = 0.0f;
            }
            o0.x = vv[0]; o0.y = vv[1]; o0.z = vv[2]; o0.w = vv[3];
            o1.x = vv[4]; o1.y = vv[5]; o1.z = vv[6]; o1.w = vv[7];
            *(float4*)&Y[e_my + i][j_my]     = o0;
            *(float4*)&Y[e_my + i][j_my + 4] = o1;
        }
    }

    // ---------------- layer 2: feat = relu(Y @ w2 + b2), K=128 --------------
    for (int kt = 0; kt < 4; ++kt) {
        __syncthreads();
        {
            const float4* wsrc = (const float4*)(w2 + (size_t)kt * TK * HH);
            float4* wdst = (float4*)&Ws[0][0];
            #pragma unroll
            for (int i = 0; i < 4; ++i) wdst[t + i * 256] = wsrc[t + i * 256];
        }
        __syncthreads();
        #pragma unroll 4
        for (int k = 0; k < TK; ++k) {
            const int kg = kt * TK + k;
            const float a0 = Y[e_my + 0][kg];
            const float a1 = Y[e_my + 1][kg];
            const float a2 = Y[e_my + 2][kg];
            const float a3 = Y[e_my + 3][kg];
            const float4 wA = *(const float4*)&Ws[k][j_my];
            const float4 wB = *(const float4*)&Ws[k][j_my + 4];
            const float wv[8] = {wA.x, wA.y, wA.z, wA.w, wB.x, wB.y, wB.z, wB.w};
            #pragma unroll
            for (int j = 0; j < 8; ++j) {
                acc[0][j] += a0 * wv[j];
                acc[1][j] += a1 * wv[j];
                acc[2][j] += a2 * wv[j];
                acc[3][j] += a3 * wv[j];
            }
        }
    }
    __syncthreads();   // all Y (y1) reads done -> safe to overwrite with feat

    // layer-2 epilogue: relu + bias -> Y (feat), atomic scatter agg
    {
        const float4 bA = *(const float4*)&b2[j_my];
        const float4 bB = *(const float4*)&b2[j_my + 4];
        const float bv[8] = {bA.x, bA.y, bA.z, bA.w, bB.x, bB.y, bB.z, bB.w};
        #pragma unroll
        for (int i = 0; i < 4; ++i) {
            const int e = e_my + i;
            float vv[8];
            #pragma unroll
            for (int j = 0; j < 8; ++j) {
                vv[j] = fmaxf(acc[i][j] + bv[j], 0.0f);
                acc[i][j] = 0.0f;
            }
            float4 o0, o1;
            o0.x = vv[0]; o0.y = vv[1]; o0.z = vv[2]; o0.w = vv[3];
            o1.x = vv[4]; o1.y = vv[5]; o1.z = vv[6]; o1.w = vv[7];
            *(float4*)&Y[e][j_my]     = o0;
            *(float4*)&Y[e][j_my + 4] = o1;
            float* dst = agg + ((size_t)b * NN + Rw[e]) * HH + j_my;
            #pragma unroll
            for (int j = 0; j < 8; ++j) atomicAdd(&dst[j], vv[j]);
        }
    }

    // ---------------- coord gate: g1 = relu(Y @ cw1 + cb1), K=128 -----------
    for (int kt = 0; kt < 4; ++kt) {
        __syncthreads();
        {
            const float4* wsrc = (const float4*)(cw1 + (size_t)kt * TK * HH);
            float4* wdst = (float4*)&Ws[0][0];
            #pragma unroll
            for (int i = 0; i < 4; ++i) wdst[t + i * 256] = wsrc[t + i * 256];
        }
        __syncthreads();
        #pragma unroll 4
        for (int k = 0; k < TK; ++k) {
            const int kg = kt * TK + k;
            const float a0 = Y[e_my + 0][kg];
            const float a1 = Y[e_my + 1][kg];
            const float a2 = Y[e_my + 2][kg];
            const float a3 = Y[e_my + 3][kg];
            const float4 wA = *(const float4*)&Ws[k][j_my];
            const float4 wB = *(const float4*)&Ws[k][j_my + 4];
            const float wv[8] = {wA.x, wA.y, wA.z, wA.w, wB.x, wB.y, wB.z, wB.w};
            #pragma unroll
            for (int j = 0; j < 8; ++j) {
                acc[0][j] += a0 * wv[j];
                acc[1][j] += a1 * wv[j];
                acc[2][j] += a2 * wv[j];
                acc[3][j] += a3 * wv[j];
            }
        }
    }

    // gate epilogue: relu(acc + cb1) . cw2  -> reduce over j -> aggt atomics
    {
        const float4 bA = *(const float4*)&cb1[j_my];
        const float4 bB = *(const float4*)&cb1[j_my + 4];
        const float4 cA = *(const float4*)&cw2[j_my];
        const float4 cB = *(const float4*)&cw2[j_my + 4];
        const float bv[8] = {bA.x, bA.y, bA.z, bA.w, bB.x, bB.y, bB.z, bB.w};
        const float cv[8] = {cA.x, cA.y, cA.z, cA.w, cB.x, cB.y, cB.z, cB.w};
        float gp[4];
        #pragma unroll
        for (int i = 0; i < 4; ++i) {
            float s = 0.0f;
            #pragma unroll
            for (int j = 0; j < 8; ++j)
                s += fmaxf(acc[i][j] + bv[j], 0.0f) * cv[j];
            gp[i] = s;
        }
        #pragma unroll
        for (int m = 1; m < 16; m <<= 1) {
            #pragma unroll
            for (int i = 0; i < 4; ++i) gp[i] += __shfl_xor(gp[i], m, 64);
        }
        if (tx == 0) {
            #pragma unroll
            for (int i = 0; i < 4; ++i) {
                const int e = e_my + i;
                float* dst = aggt + ((size_t)b * NN + Rw[e]) * 3;
                atomicAdd(&dst[0], CD[e][0] * gp[i]);
                atomicAdd(&dst[1], CD[e][1] * gp[i]);
                atomicAdd(&dst[2], CD[e][2] * gp[i]);
            }
        }
    }
}

// ---------------------------------------------------------------------------
// Node kernel: a = [others, h, agg] (384); o = relu(a@nw1+nb1)@nw2+nb2;
// out[:, :128] = h + o ; out[:, 128:131] = coord + aggt/max(cnt,1)
// ---------------------------------------------------------------------------
__global__ __launch_bounds__(256, 2)
void node_kernel(const float* __restrict__ h, const float* __restrict__ coord,
                 const float* __restrict__ others,
                 const float* __restrict__ nw1, const float* __restrict__ nb1,
                 const float* __restrict__ nw2, const float* __restrict__ nb2,
                 const float* __restrict__ agg, const float* __restrict__ aggt,
                 const float* __restrict__ cnt, float* __restrict__ out)
{
    __shared__ float As[TE][ASTRIDE];
    __shared__ float Ws[TK][HH];
    __shared__ float Y[TE][YSTRIDE];

    const int t  = threadIdx.x;
    const int tx = t & 15;
    const int ty = t >> 4;
    const int b  = blockIdx.y;
    const int n0 = blockIdx.x * TE;

    const int se = t >> 2;
    const int sq = t & 3;
    const int sn = min(n0 + se, NN - 1);   // clamp for tail tile

    float acc[4][8];
    #pragma unroll
    for (int i = 0; i < 4; ++i)
        #pragma unroll
        for (int j = 0; j < 8; ++j) acc[i][j] = 0.0f;

    const int e_my = ty * 4;
    const int j_my = tx * 8;

    // layer 1: K=384 (others | h | agg)
    for (int kt = 0; kt < 12; ++kt) {
        __syncthreads();
        {
            const float* src = (kt < 4) ? others : (kt < 8) ? h : agg;
            const int koff = (kt & 3) * TK + sq * 8;
            const float* p = src + ((size_t)b * NN + sn) * HH + koff;
            *(float4*)&As[se][sq * 8]     = *(const float4*)p;
            *(float4*)&As[se][sq * 8 + 4] = *(const float4*)(p + 4);
        }
        {
            const float4* wsrc = (const float4*)(nw1 + (size_t)kt * TK * HH);
            float4* wdst = (float4*)&Ws[0][0];
            #pragma unroll
            for (int i = 0; i < 4; ++i) wdst[t + i * 256] = wsrc[t + i * 256];
        }
        __syncthreads();
        #pragma unroll 4
        for (int k = 0; k < TK; ++k) {
            const float a0 = As[e_my + 0][k];
            const float a1 = As[e_my + 1][k];
            const float a2 = As[e_my + 2][k];
            const float a3 = As[e_my + 3][k];
            const float4 wA = *(const float4*)&Ws[k][j_my];
            const float4 wB = *(const float4*)&Ws[k][j_my + 4];
            const float wv[8] = {wA.x, wA.y, wA.z, wA.w, wB.x, wB.y, wB.z, wB.w};
            #pragma unroll
            for (int j = 0; j < 8; ++j) {
                acc[0][j] += a0 * wv[j];
                acc[1][j] += a1 * wv[j];
                acc[2][j] += a2 * wv[j];
                acc[3][j] += a3 * wv[j];
            }
        }
    }

    // epilogue 1: relu + bias -> Y
    {
        const float4 bA = *(const float4*)&nb1[j_my];
        const float4 bB = *(const float4*)&nb1[j_my + 4];
        const float bv[8] = {bA.x, bA.y, bA.z, bA.w, bB.x, bB.y, bB.z, bB.w};
        #pragma unroll
        for (int i = 0; i < 4; ++i) {
            float vv[8];
            #pragma unroll
            for (int j = 0; j < 8; ++j) {
                vv[j] = fmaxf(acc[i][j] + bv[j], 0.0f);
                acc[i][j] = 0.0f;
            }
            float4 o0, o1;
            o0.x = vv[0]; o0.y = vv[1]; o0.z = vv[2]; o0.w = vv[3];
            o1.x = vv[4]; o1.y = vv[5]; o1.z = vv[6]; o1.w = vv[7];
            *(float4*)&Y[e_my + i][j_my]     = o0;
            *(float4*)&Y[e_my + i][j_my + 4] = o1;
        }
    }

    // layer 2: K=128
    for (int kt = 0; kt < 4; ++kt) {
        __syncthreads();
        {
            const float4* wsrc = (const float4*)(nw2 + (size_t)kt * TK * HH);
            float4* wdst = (float4*)&Ws[0][0];
            #pragma unroll
            for (int i = 0; i < 4; ++i) wdst[t + i * 256] = wsrc[t + i * 256];
        }
        __syncthreads();
        #pragma unroll 4
        for (int k = 0; k < TK; ++k) {
            const int kg = kt * TK + k;
            const float a0 = Y[e_my + 0][kg];
            const float a1 = Y[e_my + 1][kg];
            const float a2 = Y[e_my + 2][kg];
            const float a3 = Y[e_my + 3][kg];
            const float4 wA = *(const float4*)&Ws[k][j_my];
            const float4 wB = *(const float4*)&Ws[k][j_my + 4];
            const float wv[8] = {wA.x, wA.y, wA.z, wA.w, wB.x, wB.y, wB.z, wB.w};
            #pragma unroll
            for (int j = 0; j < 8; ++j) {
                acc[0][j] += a0 * wv[j];
                acc[1][j] += a1 * wv[j];
                acc[2][j] += a2 * wv[j];
                acc[3][j] += a3 * wv[j];
            }
        }
    }

    // final epilogue: h_out = h + (acc + nb2); coord_out
    {
        const float4 bA = *(const float4*)&nb2[j_my];
        const float4 bB = *(const float4*)&nb2[j_my + 4];
        const float bv[8] = {bA.x, bA.y, bA.z, bA.w, bB.x, bB.y, bB.z, bB.w};
        #pragma unroll
        for (int i = 0; i < 4; ++i) {
            const int n = n0 + e_my + i;
            if (n < NN) {
                const float* hp = h + ((size_t)b * NN + n) * HH + j_my;
                float* op = out + ((size_t)b * NN + n) * 131 + j_my;
                #pragma unroll
                for (int j = 0; j < 8; ++j) op[j] = hp[j] + acc[i][j] + bv[j];
            }
        }
        if (tx == 0) {
            #pragma unroll
            for (int i = 0; i < 4; ++i) {
                const int n = n0 + e_my + i;
                if (n < NN) {
                    const float rinv = 1.0f / fmaxf(cnt[n], 1.0f);
                    const float* cp = coord + ((size_t)b * NN + n) * 3;
                    const float* ap = aggt + ((size_t)b * NN + n) * 3;
                    float* op = out + ((size_t)b * NN + n) * 131 + HH;
                    op[0] = cp[0] + ap[0] * rinv;
                    op[1] = cp[1] + ap[1] * rinv;
                    op[2] = cp[2] + ap[2] * rinv;
                }
            }
        }
    }
}

extern "C" void kernel_launch(void* const* d_in, const int* in_sizes, int n_in,
                              void* d_out, int out_size, void* d_ws, size_t ws_size,
                              hipStream_t stream)
{
    const float* h      = (const float*)d_in[0];
    const float* coord  = (const float*)d_in[1];
    const float* others = (const float*)d_in[2];
    const int*   eidx   = (const int*)d_in[3];
    const float* w1  = (const float*)d_in[4];
    const float* b1  = (const float*)d_in[5];
    const float* w2  = (const float*)d_in[6];
    const float* b2  = (const float*)d_in[7];
    const float* nw1 = (const float*)d_in[8];
    const float* nb1 = (const float*)d_in[9];
    const float* nw2 = (const float*)d_in[10];
    const float* nb2 = (const float*)d_in[11];
    const float* cw1 = (const float*)d_in[12];
    const float* cb1 = (const float*)d_in[13];
    const float* cw2 = (const float*)d_in[14];
    float* out = (float*)d_out;

    float* agg  = (float*)d_ws;                        // B*N*H
    float* aggt = agg + (size_t)BN * NN * HH;          // B*N*3
    float* cnt  = aggt + (size_t)BN * NN * 3;          // N

    const size_t zero_bytes =
        ((size_t)BN * NN * HH + (size_t)BN * NN * 3 + NN) * sizeof(float);
    hipMemsetAsync(d_ws, 0, zero_bytes, stream);

    dim3 blk(256);
    dim3 eg(NE / TE, BN);
    edge_kernel<<<eg, blk, 0, stream>>>(h, coord, eidx, w1, b1, w2, b2,
                                        cw1, cb1, cw2, agg, aggt, cnt);
    dim3 ng((NN + TE - 1) / TE, BN);
    node_kernel<<<ng, blk, 0, stream>>>(h, coord, others, nw1, nb1, nw2, nb2,
                                        agg, aggt, cnt, out);
}

// Round 3
// 697.163 us; speedup vs baseline: 4.8363x; 4.8363x over previous
//
#include <hip/hip_runtime.h>
#include <cstddef>

#define BN 2
#define NN 20000
#define NE 400000
#define HH 128

#define TE 64
#define TK 32
#define ASTRIDE 36
#define YSTRIDE 132

typedef __attribute__((ext_vector_type(8))) short bf16x8;
typedef __attribute__((ext_vector_type(4))) float f32x4;
typedef unsigned short ushort_t;

__device__ __forceinline__ unsigned short f2b(float f) {
    unsigned u = __float_as_uint(f);
    unsigned r = (u + 0x7FFFu + ((u >> 16) & 1u)) >> 16;
    return (unsigned short)r;
}

__device__ __forceinline__ void gll16(const void* g, void* l) {
    __builtin_amdgcn_global_load_lds(
        (const __attribute__((address_space(1))) unsigned int*)g,
        (__attribute__((address_space(3))) unsigned int*)l,
        16, 0, 0);
}

// ---------------------------------------------------------------------------
// prep: h (fp32) -> bf16, 4 elems/thread
// ---------------------------------------------------------------------------
__global__ void cvt_h_kernel(const float4* __restrict__ src, uint2* __restrict__ dst, int n4) {
    int i = blockIdx.x * 256 + threadIdx.x;
    if (i >= n4) return;
    float4 v = src[i];
    uint2 o;
    o.x = (unsigned)f2b(v.x) | ((unsigned)f2b(v.y) << 16);
    o.y = (unsigned)f2b(v.z) | ((unsigned)f2b(v.w) << 16);
    dst[i] = o;
}

// ---------------------------------------------------------------------------
// prep: pack W[K][128] fp32 -> fragment-order bf16.
// slot = (((c*2 + kt2)*8 + nt)*64 + lane); element j: k = c*64+kt2*32+(lane>>4)*8+j,
// col = nt*16 + (lane&15).  (Same k-bijection used for A and B loads.)
// ---------------------------------------------------------------------------
__global__ void pack_w_kernel(const float* __restrict__ W, ushort_t* __restrict__ dst, int K) {
    int slot = blockIdx.x * 256 + threadIdx.x;
    int total = (K >> 6) * 1024;
    if (slot >= total) return;
    int l = slot & 63, nt = (slot >> 6) & 7, kt2 = (slot >> 9) & 1, c = slot >> 10;
    int col = nt * 16 + (l & 15);
    int k0 = c * 64 + kt2 * 32 + ((l >> 4) * 8);
    unsigned out[4];
    #pragma unroll
    for (int p = 0; p < 4; ++p) {
        unsigned lo = f2b(W[(size_t)(k0 + 2 * p) * HH + col]);
        unsigned hi = f2b(W[(size_t)(k0 + 2 * p + 1) * HH + col]);
        out[p] = lo | (hi << 16);
    }
    uint4* d = (uint4*)&dst[(size_t)slot * 8];
    *d = make_uint4(out[0], out[1], out[2], out[3]);
}

// ---------------------------------------------------------------------------
// Edge kernel: 64 edges/block, 4 waves, MFMA 16x16x32 bf16, fp32 accum.
// ---------------------------------------------------------------------------
__global__ __launch_bounds__(256, 3)
void edge_kernel(const ushort_t* __restrict__ hbf, const float* __restrict__ coord,
                 const int* __restrict__ eidx,
                 const ushort_t* __restrict__ w1p, const ushort_t* __restrict__ w2p,
                 const ushort_t* __restrict__ cw1p,
                 const float* __restrict__ w1, const float* __restrict__ b1,
                 const float* __restrict__ b2, const float* __restrict__ cb1,
                 const float* __restrict__ cw2,
                 float* __restrict__ agg, float* __restrict__ aggt,
                 float* __restrict__ cnt)
{
    __shared__ ushort_t FA[4 * 4 * 64 * 8];   // frag-order A: [ktile4][mtile4][lane][8]
    __shared__ ushort_t WB[2 * 8 * 64 * 8];   // frag-order W K=64 chunk: [kt2][nt8][lane][8]
    __shared__ ushort_t YN[64 * 136];         // natural bf16 activations [row][col], pad->136
    __shared__ int Rw[64], Cw[64];
    __shared__ float CD3[64 * 3];
    __shared__ float Rad[64];
    __shared__ float GT[64];

    const int t = threadIdx.x;
    const int l = t & 63;
    const int w = t >> 6;
    const int b = blockIdx.y;
    const int e0 = blockIdx.x * 64;

    if (t < 64) {
        int r = eidx[e0 + t], c = eidx[NE + e0 + t];
        Rw[t] = r; Cw[t] = c; GT[t] = 0.0f;
        const float* cr = coord + ((size_t)b * NN + r) * 3;
        const float* cc = coord + ((size_t)b * NN + c) * 3;
        float d0 = cr[0] - cc[0], d1 = cr[1] - cc[1], d2 = cr[2] - cc[2];
        CD3[t * 3] = d0; CD3[t * 3 + 1] = d1; CD3[t * 3 + 2] = d2;
        Rad[t] = d0 * d0 + d1 * d1 + d2 * d2;
        if (b == 0) atomicAdd(&cnt[r], 1.0f);
    }
    __syncthreads();

    const int nt0 = w * 2, nt1 = w * 2 + 1;
    const int col0 = nt0 * 16 + (l & 15);
    const int col1 = col0 + 16;

    f32x4 acc[4][2];
    #pragma unroll
    for (int mt = 0; mt < 4; ++mt) { acc[mt][0] = (f32x4)0.0f; acc[mt][1] = (f32x4)0.0f; }

    auto stage_wb = [&](const ushort_t* src) {
        #pragma unroll
        for (int i = 0; i < 4; ++i)
            gll16(src + ((size_t)((i * 4 + w) * 64 + l)) * 8, (void*)&WB[((i * 4 + w) * 64) * 8]);
    };
    auto stage_fa = [&](const int* IA) {
        const ushort_t* hb = hbf + ((size_t)b * NN + IA[w * 16 + (l & 15)]) * HH + ((l >> 4) * 8);
        #pragma unroll
        for (int kt = 0; kt < 4; ++kt)
            gll16(hb + kt * 32, (void*)&FA[((kt * 4 + w) * 64) * 8]);
    };
    auto mfma_fa = [&](int ktg_base) {
        #pragma unroll
        for (int kt2 = 0; kt2 < 2; ++kt2) {
            const int ktg = ktg_base + kt2;
            bf16x8 bb0 = *(const bf16x8*)&WB[((kt2 * 8 + nt0) * 64 + l) * 8];
            bf16x8 bb1 = *(const bf16x8*)&WB[((kt2 * 8 + nt1) * 64 + l) * 8];
            #pragma unroll
            for (int mt = 0; mt < 4; ++mt) {
                bf16x8 a = *(const bf16x8*)&FA[((ktg * 4 + mt) * 64 + l) * 8];
                acc[mt][0] = __builtin_amdgcn_mfma_f32_16x16x32_bf16(a, bb0, acc[mt][0], 0, 0, 0);
                acc[mt][1] = __builtin_amdgcn_mfma_f32_16x16x32_bf16(a, bb1, acc[mt][1], 0, 0, 0);
            }
        }
    };
    auto mfma_yn = [&](int c2) {
        #pragma unroll
        for (int kt2 = 0; kt2 < 2; ++kt2) {
            const int k0 = (c2 * 2 + kt2) * 32 + ((l >> 4) * 8);
            bf16x8 bb0 = *(const bf16x8*)&WB[((kt2 * 8 + nt0) * 64 + l) * 8];
            bf16x8 bb1 = *(const bf16x8*)&WB[((kt2 * 8 + nt1) * 64 + l) * 8];
            #pragma unroll
            for (int mt = 0; mt < 4; ++mt) {
                const int row = mt * 16 + (l & 15);
                bf16x8 a = *(const bf16x8*)&YN[row * 136 + k0];
                acc[mt][0] = __builtin_amdgcn_mfma_f32_16x16x32_bf16(a, bb0, acc[mt][0], 0, 0, 0);
                acc[mt][1] = __builtin_amdgcn_mfma_f32_16x16x32_bf16(a, bb1, acc[mt][1], 0, 0, 0);
            }
        }
    };

    // ---------------- L1: y1 = relu([h_row|h_col|rad] @ w1 + b1) ------------
    stage_fa(Rw); stage_wb(w1p);
    __syncthreads();
    mfma_fa(0);
    __syncthreads();
    stage_wb(w1p + 8192);
    __syncthreads();
    mfma_fa(2);
    __syncthreads();
    stage_fa(Cw); stage_wb(w1p + 2 * 8192);
    __syncthreads();
    mfma_fa(0);
    __syncthreads();
    stage_wb(w1p + 3 * 8192);
    __syncthreads();
    mfma_fa(2);
    __syncthreads();

    // epilogue 1 (radial + bias + relu -> YN) overlapped with W2 chunk0 stage
    stage_wb(w2p);
    {
        const float w1r0 = w1[256 * HH + col0];
        const float w1r1 = w1[256 * HH + col1];
        const float bb0 = b1[col0], bb1 = b1[col1];
        #pragma unroll
        for (int mt = 0; mt < 4; ++mt)
            #pragma unroll
            for (int j = 0; j < 4; ++j) {
                const int row = mt * 16 + ((l >> 4) * 4) + j;
                const float r = Rad[row];
                float v0 = fmaxf(acc[mt][0][j] + r * w1r0 + bb0, 0.0f);
                float v1 = fmaxf(acc[mt][1][j] + r * w1r1 + bb1, 0.0f);
                YN[row * 136 + col0] = f2b(v0);
                YN[row * 136 + col1] = f2b(v1);
                acc[mt][0][j] = 0.0f; acc[mt][1][j] = 0.0f;
            }
    }
    __syncthreads();

    // ---------------- L2: feat = relu(y1 @ w2 + b2) -------------------------
    mfma_yn(0);
    __syncthreads();
    stage_wb(w2p + 8192);
    __syncthreads();
    mfma_yn(1);
    __syncthreads();

    // feat epilogue (overwrite YN, atomic agg scatter), overlap CW1 chunk0 stage
    stage_wb(cw1p);
    {
        const float bb0 = b2[col0], bb1 = b2[col1];
        #pragma unroll
        for (int mt = 0; mt < 4; ++mt)
            #pragma unroll
            for (int j = 0; j < 4; ++j) {
                const int row = mt * 16 + ((l >> 4) * 4) + j;
                float v0 = fmaxf(acc[mt][0][j] + bb0, 0.0f);
                float v1 = fmaxf(acc[mt][1][j] + bb1, 0.0f);
                YN[row * 136 + col0] = f2b(v0);
                YN[row * 136 + col1] = f2b(v1);
                const size_t base = ((size_t)b * NN + Rw[row]) * HH;
                atomicAdd(&agg[base + col0], v0);
                atomicAdd(&agg[base + col1], v1);
                acc[mt][0][j] = 0.0f; acc[mt][1][j] = 0.0f;
            }
    }
    __syncthreads();

    // ---------------- L3: g1 = relu(feat @ cw1 + cb1) -----------------------
    mfma_yn(0);
    __syncthreads();
    stage_wb(cw1p + 8192);
    __syncthreads();
    mfma_yn(1);

    // gate epilogue: gate = g1 . cw2 ; aggt scatter
    {
        const float cbA = cb1[col0], cbB = cb1[col1];
        const float cwA = cw2[col0], cwB = cw2[col1];
        #pragma unroll
        for (int mt = 0; mt < 4; ++mt)
            #pragma unroll
            for (int j = 0; j < 4; ++j) {
                float g = fmaxf(acc[mt][0][j] + cbA, 0.0f) * cwA
                        + fmaxf(acc[mt][1][j] + cbB, 0.0f) * cwB;
                g += __shfl_xor(g, 1);
                g += __shfl_xor(g, 2);
                g += __shfl_xor(g, 4);
                g += __shfl_xor(g, 8);
                if ((l & 15) == 0)
                    atomicAdd(&GT[mt * 16 + ((l >> 4) * 4) + j], g);
            }
    }
    __syncthreads();
    if (t < 64) {
        const float gate = GT[t];
        const size_t base = ((size_t)b * NN + Rw[t]) * 3;
        atomicAdd(&aggt[base + 0], CD3[t * 3 + 0] * gate);
        atomicAdd(&aggt[base + 1], CD3[t * 3 + 1] * gate);
        atomicAdd(&aggt[base + 2], CD3[t * 3 + 2] * gate);
    }
}

// ---------------------------------------------------------------------------
// Node kernel (fp32)
// ---------------------------------------------------------------------------
__global__ __launch_bounds__(256, 2)
void node_kernel(const float* __restrict__ h, const float* __restrict__ coord,
                 const float* __restrict__ others,
                 const float* __restrict__ nw1, const float* __restrict__ nb1,
                 const float* __restrict__ nw2, const float* __restrict__ nb2,
                 const float* __restrict__ agg, const float* __restrict__ aggt,
                 const float* __restrict__ cnt, float* __restrict__ out)
{
    __shared__ float As[TE][ASTRIDE];
    __shared__ float Ws[TK][HH];
    __shared__ float Y[TE][YSTRIDE];

    const int t  = threadIdx.x;
    const int tx = t & 15;
    const int ty = t >> 4;
    const int b  = blockIdx.y;
    const int n0 = blockIdx.x * TE;

    const int se = t >> 2;
    const int sq = t & 3;
    const int sn = min(n0 + se, NN - 1);

    float acc[4][8];
    #pragma unroll
    for (int i = 0; i < 4; ++i)
        #pragma unroll
        for (int j = 0; j < 8; ++j) acc[i][j] = 0.0f;

    const int e_my = ty * 4;
    const int j_my = tx * 8;

    for (int kt = 0; kt < 12; ++kt) {
        __syncthreads();
        {
            const float* src = (kt < 4) ? others : (kt < 8) ? h : agg;
            const int koff = (kt & 3) * TK + sq * 8;
            const float* p = src + ((size_t)b * NN + sn) * HH + koff;
            *(float4*)&As[se][sq * 8]     = *(const float4*)p;
            *(float4*)&As[se][sq * 8 + 4] = *(const float4*)(p + 4);
        }
        {
            const float4* wsrc = (const float4*)(nw1 + (size_t)kt * TK * HH);
            float4* wdst = (float4*)&Ws[0][0];
            #pragma unroll
            for (int i = 0; i < 4; ++i) wdst[t + i * 256] = wsrc[t + i * 256];
        }
        __syncthreads();
        #pragma unroll 4
        for (int k = 0; k < TK; ++k) {
            const float a0 = As[e_my + 0][k];
            const float a1 = As[e_my + 1][k];
            const float a2 = As[e_my + 2][k];
            const float a3 = As[e_my + 3][k];
            const float4 wA = *(const float4*)&Ws[k][j_my];
            const float4 wB = *(const float4*)&Ws[k][j_my + 4];
            const float wv[8] = {wA.x, wA.y, wA.z, wA.w, wB.x, wB.y, wB.z, wB.w};
            #pragma unroll
            for (int j = 0; j < 8; ++j) {
                acc[0][j] += a0 * wv[j];
                acc[1][j] += a1 * wv[j];
                acc[2][j] += a2 * wv[j];
                acc[3][j] += a3 * wv[j];
            }
        }
    }

    {
        const float4 bA = *(const float4*)&nb1[j_my];
        const float4 bB = *(const float4*)&nb1[j_my + 4];
        const float bv[8] = {bA.x, bA.y, bA.z, bA.w, bB.x, bB.y, bB.z, bB.w};
        #pragma unroll
        for (int i = 0; i < 4; ++i) {
            float vv[8];
            #pragma unroll
            for (int j = 0; j < 8; ++j) {
                vv[j] = fmaxf(acc[i][j] + bv[j], 0.0f);
                acc[i][j] = 0.0f;
            }
            float4 o0, o1;
            o0.x = vv[0]; o0.y = vv[1]; o0.z = vv[2]; o0.w = vv[3];
            o1.x = vv[4]; o1.y = vv[5]; o1.z = vv[6]; o1.w = vv[7];
            *(float4*)&Y[e_my + i][j_my]     = o0;
            *(float4*)&Y[e_my + i][j_my + 4] = o1;
        }
    }

    for (int kt = 0; kt < 4; ++kt) {
        __syncthreads();
        {
            const float4* wsrc = (const float4*)(nw2 + (size_t)kt * TK * HH);
            float4* wdst = (float4*)&Ws[0][0];
            #pragma unroll
            for (int i = 0; i < 4; ++i) wdst[t + i * 256] = wsrc[t + i * 256];
        }
        __syncthreads();
        #pragma unroll 4
        for (int k = 0; k < TK; ++k) {
            const int kg = kt * TK + k;
            const float a0 = Y[e_my + 0][kg];
            const float a1 = Y[e_my + 1][kg];
            const float a2 = Y[e_my + 2][kg];
            const float a3 = Y[e_my + 3][kg];
            const float4 wA = *(const float4*)&Ws[k][j_my];
            const float4 wB = *(const float4*)&Ws[k][j_my + 4];
            const float wv[8] = {wA.x, wA.y, wA.z, wA.w, wB.x, wB.y, wB.z, wB.w};
            #pragma unroll
            for (int j = 0; j < 8; ++j) {
                acc[0][j] += a0 * wv[j];
                acc[1][j] += a1 * wv[j];
                acc[2][j] += a2 * wv[j];
                acc[3][j] += a3 * wv[j];
            }
        }
    }

    {
        const float4 bA = *(const float4*)&nb2[j_my];
        const float4 bB = *(const float4*)&nb2[j_my + 4];
        const float bv[8] = {bA.x, bA.y, bA.z, bA.w, bB.x, bB.y, bB.z, bB.w};
        #pragma unroll
        for (int i = 0; i < 4; ++i) {
            const int n = n0 + e_my + i;
            if (n < NN) {
                const float* hp = h + ((size_t)b * NN + n) * HH + j_my;
                float* op = out + ((size_t)b * NN + n) * 131 + j_my;
                #pragma unroll
                for (int j = 0; j < 8; ++j) op[j] = hp[j] + acc[i][j] + bv[j];
            }
        }
        if (tx == 0) {
            #pragma unroll
            for (int i = 0; i < 4; ++i) {
                const int n = n0 + e_my + i;
                if (n < NN) {
                    const float rinv = 1.0f / fmaxf(cnt[n], 1.0f);
                    const float* cp = coord + ((size_t)b * NN + n) * 3;
                    const float* ap = aggt + ((size_t)b * NN + n) * 3;
                    float* op = out + ((size_t)b * NN + n) * 131 + HH;
                    op[0] = cp[0] + ap[0] * rinv;
                    op[1] = cp[1] + ap[1] * rinv;
                    op[2] = cp[2] + ap[2] * rinv;
                }
            }
        }
    }
}

extern "C" void kernel_launch(void* const* d_in, const int* in_sizes, int n_in,
                              void* d_out, int out_size, void* d_ws, size_t ws_size,
                              hipStream_t stream)
{
    const float* h      = (const float*)d_in[0];
    const float* coord  = (const float*)d_in[1];
    const float* others = (const float*)d_in[2];
    const int*   eidx   = (const int*)d_in[3];
    const float* w1  = (const float*)d_in[4];
    const float* b1  = (const float*)d_in[5];
    const float* w2  = (const float*)d_in[6];
    const float* b2  = (const float*)d_in[7];
    const float* nw1 = (const float*)d_in[8];
    const float* nb1 = (const float*)d_in[9];
    const float* nw2 = (const float*)d_in[10];
    const float* nb2 = (const float*)d_in[11];
    const float* cw1 = (const float*)d_in[12];
    const float* cb1 = (const float*)d_in[13];
    const float* cw2 = (const float*)d_in[14];
    float* out = (float*)d_out;

    // ws layout (fp32 region first, then bf16 regions) — total ~31.4 MB
    float* agg  = (float*)d_ws;                       // 5,120,000 f32
    float* aggt = agg + (size_t)BN * NN * HH;         // 120,000 f32
    float* cnt  = aggt + (size_t)BN * NN * 3;         // 20,000 f32
    ushort_t* hbf  = (ushort_t*)(cnt + NN);           // 5,120,000 bf16
    ushort_t* w1p  = hbf + (size_t)BN * NN * HH;      // 32768 (K=256 packed)
    ushort_t* w2p  = w1p + 32768;                     // 16384 (K=128)
    ushort_t* cw1p = w2p + 16384;                     // 16384

    const size_t zero_bytes =
        ((size_t)BN * NN * HH + (size_t)BN * NN * 3 + NN) * sizeof(float);
    hipMemsetAsync(d_ws, 0, zero_bytes, stream);

    const int n4 = (BN * NN * HH) / 4;
    cvt_h_kernel<<<n4 / 256, 256, 0, stream>>>((const float4*)h, (uint2*)hbf, n4);
    pack_w_kernel<<<16, 256, 0, stream>>>(w1, w1p, 256);
    pack_w_kernel<<<8, 256, 0, stream>>>(w2, w2p, 128);
    pack_w_kernel<<<8, 256, 0, stream>>>(cw1, cw1p, 128);

    dim3 eg(NE / 64, BN);
    edge_kernel<<<eg, 256, 0, stream>>>(hbf, coord, eidx, w1p, w2p, cw1p,
                                        w1, b1, b2, cb1, cw2, agg, aggt, cnt);

    dim3 ng((NN + TE - 1) / TE, BN);
    node_kernel<<<ng, 256, 0, stream>>>(h, coord, others, nw1, nb1, nw2, nb2,
                                        agg, aggt, cnt, out);
}

// Round 4
// 641.621 us; speedup vs baseline: 5.2549x; 1.0866x over previous
//
#include <hip/hip_runtime.h>
#include <cstddef>

#define BN 2
#define NN 20000
#define NE 400000
#define HH 128

typedef __attribute__((ext_vector_type(8))) short bf16x8;
typedef __attribute__((ext_vector_type(4))) float f32x4;
typedef unsigned short ushort_t;

__device__ __forceinline__ unsigned short f2b(float f) {
    unsigned u = __float_as_uint(f);
    unsigned r = (u + 0x7FFFu + ((u >> 16) & 1u)) >> 16;
    return (unsigned short)r;
}

__device__ __forceinline__ void gll16(const void* g, void* l) {
    __builtin_amdgcn_global_load_lds(
        (const __attribute__((address_space(1))) unsigned int*)g,
        (__attribute__((address_space(3))) unsigned int*)l,
        16, 0, 0);
}

// ---------------------------------------------------------------------------
// prep: h (fp32) -> bf16
// ---------------------------------------------------------------------------
__global__ void cvt_h_kernel(const float4* __restrict__ src, uint2* __restrict__ dst, int n4) {
    int i = blockIdx.x * 256 + threadIdx.x;
    if (i >= n4) return;
    float4 v = src[i];
    uint2 o;
    o.x = (unsigned)f2b(v.x) | ((unsigned)f2b(v.y) << 16);
    o.y = (unsigned)f2b(v.z) | ((unsigned)f2b(v.w) << 16);
    dst[i] = o;
}

// ---------------------------------------------------------------------------
// prep: pack W[K][128] fp32 -> fragment-order bf16.
// slot = (ktg*8 + nt)*64 + lane ; element j: k = ktg*32 + (lane>>4)*8 + j,
// col = nt*16 + (lane&15).
// ---------------------------------------------------------------------------
__global__ void pack_w_kernel(const float* __restrict__ W, ushort_t* __restrict__ dst, int K) {
    int slot = blockIdx.x * 256 + threadIdx.x;
    int total = (K >> 6) * 1024;
    if (slot >= total) return;
    int l = slot & 63, nt = (slot >> 6) & 7, kt2 = (slot >> 9) & 1, c = slot >> 10;
    int col = nt * 16 + (l & 15);
    int k0 = c * 64 + kt2 * 32 + ((l >> 4) * 8);
    unsigned out[4];
    #pragma unroll
    for (int p = 0; p < 4; ++p) {
        unsigned lo = f2b(W[(size_t)(k0 + 2 * p) * HH + col]);
        unsigned hi = f2b(W[(size_t)(k0 + 2 * p + 1) * HH + col]);
        out[p] = lo | (hi << 16);
    }
    uint4* d = (uint4*)&dst[(size_t)slot * 8];
    *d = make_uint4(out[0], out[1], out[2], out[3]);
}

// ===========================================================================
// Edge kernel: 128 edges/block, 4 waves, weights in VGPRs, fp32 accum.
// Barriers per tile: ~8 (vs ~16 per 64 edges before).
// ===========================================================================
#define MFMA_FA(BB)                                                               \
    _Pragma("unroll")                                                             \
    for (int ktg = 0; ktg < 4; ++ktg) {                                           \
        _Pragma("unroll")                                                         \
        for (int mt = 0; mt < 8; ++mt) {                                          \
            bf16x8 a = *(const bf16x8*)&FA[((ktg * 8 + mt) * 64 + l) * 8];        \
            acc[mt][0] = __builtin_amdgcn_mfma_f32_16x16x32_bf16(                 \
                a, bw[(BB) + ktg * 2 + 0], acc[mt][0], 0, 0, 0);                  \
            acc[mt][1] = __builtin_amdgcn_mfma_f32_16x16x32_bf16(                 \
                a, bw[(BB) + ktg * 2 + 1], acc[mt][1], 0, 0, 0);                  \
        }                                                                         \
    }

#define MFMA_YN(BB)                                                               \
    _Pragma("unroll")                                                             \
    for (int ktg = 0; ktg < 4; ++ktg) {                                           \
        _Pragma("unroll")                                                         \
        for (int mt = 0; mt < 8; ++mt) {                                          \
            const int row_ = mt * 16 + lo16;                                      \
            bf16x8 a = *(const bf16x8*)&YN[row_ * 136 + ktg * 32 + hi4 * 8];      \
            acc[mt][0] = __builtin_amdgcn_mfma_f32_16x16x32_bf16(                 \
                a, bw[(BB) + ktg * 2 + 0], acc[mt][0], 0, 0, 0);                  \
            acc[mt][1] = __builtin_amdgcn_mfma_f32_16x16x32_bf16(                 \
                a, bw[(BB) + ktg * 2 + 1], acc[mt][1], 0, 0, 0);                  \
        }                                                                         \
    }

__global__ __launch_bounds__(256, 2)
void edge_kernel(const ushort_t* __restrict__ hbf, const float* __restrict__ coord,
                 const int* __restrict__ eidx,
                 const ushort_t* __restrict__ w1p, const ushort_t* __restrict__ w2p,
                 const ushort_t* __restrict__ cw1p,
                 const float* __restrict__ w1, const float* __restrict__ b1,
                 const float* __restrict__ b2, const float* __restrict__ cb1,
                 const float* __restrict__ cw2,
                 float* __restrict__ agg, float* __restrict__ aggt,
                 float* __restrict__ cnt)
{
    __shared__ ushort_t FA[4 * 8 * 64 * 8];   // 32 KB  [ktg][mt][lane][8]
    __shared__ ushort_t YN[128 * 136];        // 34.8 KB natural [row][col]
    __shared__ int Rw[128], Cw[128];
    __shared__ float CD3[128 * 3];
    __shared__ float Rad[128];
    __shared__ float GT[128];

    const int t = threadIdx.x;
    const int l = t & 63;
    const int w = t >> 6;
    const int b = blockIdx.y;
    const int e0 = blockIdx.x * 128;

    const int lo16 = l & 15;
    const int hi4 = l >> 4;
    const int col0 = w * 32 + lo16;
    const int col1 = col0 + 16;

    // w1 B-fragments -> 64 VGPRs (overlaps with setup below)
    bf16x8 bw[16];
    #pragma unroll
    for (int ktg = 0; ktg < 8; ++ktg) {
        bw[ktg * 2 + 0] = *(const bf16x8*)&w1p[((ktg * 8 + w * 2 + 0) * 64 + l) * 8];
        bw[ktg * 2 + 1] = *(const bf16x8*)&w1p[((ktg * 8 + w * 2 + 1) * 64 + l) * 8];
    }

    if (t < 128) {
        int r = eidx[e0 + t], c = eidx[NE + e0 + t];
        Rw[t] = r; Cw[t] = c; GT[t] = 0.0f;
        const float* cr = coord + ((size_t)b * NN + r) * 3;
        const float* cc = coord + ((size_t)b * NN + c) * 3;
        float d0 = cr[0] - cc[0], d1 = cr[1] - cc[1], d2 = cr[2] - cc[2];
        CD3[t * 3] = d0; CD3[t * 3 + 1] = d1; CD3[t * 3 + 2] = d2;
        Rad[t] = d0 * d0 + d1 * d1 + d2 * d2;
        if (b == 0) atomicAdd(&cnt[r], 1.0f);
    }

    f32x4 acc[8][2];
    #pragma unroll
    for (int mt = 0; mt < 8; ++mt) { acc[mt][0] = (f32x4)0.0f; acc[mt][1] = (f32x4)0.0f; }

    __syncthreads();   // Rw/Cw visible

    // ---- stage A row-half (K=128), frag order, via global_load_lds --------
    #pragma unroll
    for (int i = 0; i < 2; ++i) {
        const int mt = w * 2 + i;
        const ushort_t* hb = hbf + ((size_t)b * NN + Rw[mt * 16 + lo16]) * HH + hi4 * 8;
        #pragma unroll
        for (int ktg = 0; ktg < 4; ++ktg)
            gll16(hb + ktg * 32, (void*)&FA[((ktg * 8 + mt) * 64) * 8]);
    }
    __syncthreads();

    MFMA_FA(0)         // L1, k 0..127
    __syncthreads();   // FA readers done (WAR)

    // ---- stage A col-half ----
    #pragma unroll
    for (int i = 0; i < 2; ++i) {
        const int mt = w * 2 + i;
        const ushort_t* hb = hbf + ((size_t)b * NN + Cw[mt * 16 + lo16]) * HH + hi4 * 8;
        #pragma unroll
        for (int ktg = 0; ktg < 4; ++ktg)
            gll16(hb + ktg * 32, (void*)&FA[((ktg * 8 + mt) * 64) * 8]);
    }
    __syncthreads();

    MFMA_FA(8)         // L1, k 128..255

    // reuse B regs: w2 -> bw[0..7], cw1 -> bw[8..15]
    #pragma unroll
    for (int ktg = 0; ktg < 4; ++ktg) {
        bw[ktg * 2 + 0] = *(const bf16x8*)&w2p[((ktg * 8 + w * 2 + 0) * 64 + l) * 8];
        bw[ktg * 2 + 1] = *(const bf16x8*)&w2p[((ktg * 8 + w * 2 + 1) * 64 + l) * 8];
        bw[8 + ktg * 2 + 0] = *(const bf16x8*)&cw1p[((ktg * 8 + w * 2 + 0) * 64 + l) * 8];
        bw[8 + ktg * 2 + 1] = *(const bf16x8*)&cw1p[((ktg * 8 + w * 2 + 1) * 64 + l) * 8];
    }

    // ---- epilogue 1: radial + bias + relu -> YN ----
    {
        const float w1r0 = w1[256 * HH + col0];
        const float w1r1 = w1[256 * HH + col1];
        const float b10 = b1[col0], b11 = b1[col1];
        #pragma unroll
        for (int mt = 0; mt < 8; ++mt)
            #pragma unroll
            for (int j = 0; j < 4; ++j) {
                const int row = mt * 16 + hi4 * 4 + j;
                const float r = Rad[row];
                float v0 = fmaxf(acc[mt][0][j] + r * w1r0 + b10, 0.0f);
                float v1 = fmaxf(acc[mt][1][j] + r * w1r1 + b11, 0.0f);
                YN[row * 136 + col0] = f2b(v0);
                YN[row * 136 + col1] = f2b(v1);
                acc[mt][0][j] = 0.0f; acc[mt][1][j] = 0.0f;
            }
    }
    __syncthreads();

    MFMA_YN(0)         // L2: feat = y1 @ w2
    __syncthreads();   // YN readers done

    // ---- feat epilogue: relu -> YN, agg atomic scatter ----
    {
        const float b20 = b2[col0], b21 = b2[col1];
        #pragma unroll
        for (int mt = 0; mt < 8; ++mt)
            #pragma unroll
            for (int j = 0; j < 4; ++j) {
                const int row = mt * 16 + hi4 * 4 + j;
                float v0 = fmaxf(acc[mt][0][j] + b20, 0.0f);
                float v1 = fmaxf(acc[mt][1][j] + b21, 0.0f);
                YN[row * 136 + col0] = f2b(v0);
                YN[row * 136 + col1] = f2b(v1);
                const size_t base = ((size_t)b * NN + Rw[row]) * HH;
                atomicAdd(&agg[base + col0], v0);
                atomicAdd(&agg[base + col1], v1);
                acc[mt][0][j] = 0.0f; acc[mt][1][j] = 0.0f;
            }
    }
    __syncthreads();

    MFMA_YN(8)         // L3: g1 = feat @ cw1

    // ---- gate epilogue ----
    {
        const float cbA = cb1[col0], cbB = cb1[col1];
        const float cwA = cw2[col0], cwB = cw2[col1];
        #pragma unroll
        for (int mt = 0; mt < 8; ++mt)
            #pragma unroll
            for (int j = 0; j < 4; ++j) {
                float g = fmaxf(acc[mt][0][j] + cbA, 0.0f) * cwA
                        + fmaxf(acc[mt][1][j] + cbB, 0.0f) * cwB;
                g += __shfl_xor(g, 1);
                g += __shfl_xor(g, 2);
                g += __shfl_xor(g, 4);
                g += __shfl_xor(g, 8);
                if (lo16 == 0)
                    atomicAdd(&GT[mt * 16 + hi4 * 4 + j], g);
            }
    }
    __syncthreads();
    if (t < 128) {
        const float gate = GT[t];
        const size_t base = ((size_t)b * NN + Rw[t]) * 3;
        atomicAdd(&aggt[base + 0], CD3[t * 3 + 0] * gate);
        atomicAdd(&aggt[base + 1], CD3[t * 3 + 1] * gate);
        atomicAdd(&aggt[base + 2], CD3[t * 3 + 2] * gate);
    }
}

// ===========================================================================
// Node kernel: 128 nodes/block, MFMA, nw1 (K=384) in 96 VGPRs.
// a = [others | h | agg]; out = [h + mlp(a), coord + aggt/cnt]
// ===========================================================================
__global__ __launch_bounds__(256, 2)
void node_kernel(const ushort_t* __restrict__ hbf, const float* __restrict__ h,
                 const float* __restrict__ coord, const float* __restrict__ others,
                 const float* __restrict__ agg,
                 const ushort_t* __restrict__ nw1p, const ushort_t* __restrict__ nw2p,
                 const float* __restrict__ nb1, const float* __restrict__ nb2,
                 const float* __restrict__ aggt, const float* __restrict__ cnt,
                 float* __restrict__ out)
{
    __shared__ ushort_t FA[4 * 8 * 64 * 8];   // 32 KB
    __shared__ ushort_t YN[128 * 136];        // 34.8 KB

    const int t = threadIdx.x;
    const int l = t & 63;
    const int w = t >> 6;
    const int b = blockIdx.y;
    const int n0 = blockIdx.x * 128;

    const int lo16 = l & 15;
    const int hi4 = l >> 4;
    const int col0 = w * 32 + lo16;
    const int col1 = col0 + 16;

    bf16x8 bw[24];
    #pragma unroll
    for (int ktg = 0; ktg < 12; ++ktg) {
        bw[ktg * 2 + 0] = *(const bf16x8*)&nw1p[((ktg * 8 + w * 2 + 0) * 64 + l) * 8];
        bw[ktg * 2 + 1] = *(const bf16x8*)&nw1p[((ktg * 8 + w * 2 + 1) * 64 + l) * 8];
    }

    // coord output (independent of the MLP) — do it early
    if (t < 128) {
        const int n = n0 + t;
        if (n < NN) {
            const float rinv = 1.0f / fmaxf(cnt[n], 1.0f);
            const float* cp = coord + ((size_t)b * NN + n) * 3;
            const float* ap = aggt + ((size_t)b * NN + n) * 3;
            float* op = out + ((size_t)b * NN + n) * 131 + HH;
            op[0] = cp[0] + ap[0] * rinv;
            op[1] = cp[1] + ap[1] * rinv;
            op[2] = cp[2] + ap[2] * rinv;
        }
    }

    f32x4 acc[8][2];
    #pragma unroll
    for (int mt = 0; mt < 8; ++mt) { acc[mt][0] = (f32x4)0.0f; acc[mt][1] = (f32x4)0.0f; }

    // fp32 source -> bf16 frag-order LDS staging (reg convert)
    #define STAGE_CVT(SRC)                                                        \
        _Pragma("unroll")                                                         \
        for (int i = 0; i < 2; ++i) {                                             \
            const int mt = w * 2 + i;                                             \
            const int row = min(n0 + mt * 16 + lo16, NN - 1);                     \
            const float* p = (SRC) + ((size_t)b * NN + row) * HH + hi4 * 8;       \
            _Pragma("unroll")                                                     \
            for (int ktg = 0; ktg < 4; ++ktg) {                                   \
                float4 fa = *(const float4*)(p + ktg * 32);                       \
                float4 fb = *(const float4*)(p + ktg * 32 + 4);                   \
                uint4 u;                                                          \
                u.x = (unsigned)f2b(fa.x) | ((unsigned)f2b(fa.y) << 16);          \
                u.y = (unsigned)f2b(fa.z) | ((unsigned)f2b(fa.w) << 16);          \
                u.z = (unsigned)f2b(fb.x) | ((unsigned)f2b(fb.y) << 16);          \
                u.w = (unsigned)f2b(fb.z) | ((unsigned)f2b(fb.w) << 16);          \
                *(uint4*)&FA[((ktg * 8 + mt) * 64 + l) * 8] = u;                  \
            }                                                                     \
        }

    // ---- L1 phase A: others (k 0..127) ----
    STAGE_CVT(others)
    __syncthreads();
    MFMA_FA(0)
    __syncthreads();

    // ---- L1 phase B: h (k 128..255), pre-converted bf16 via gll ----
    #pragma unroll
    for (int i = 0; i < 2; ++i) {
        const int mt = w * 2 + i;
        const int row = min(n0 + mt * 16 + lo16, NN - 1);
        const ushort_t* hb = hbf + ((size_t)b * NN + row) * HH + hi4 * 8;
        #pragma unroll
        for (int ktg = 0; ktg < 4; ++ktg)
            gll16(hb + ktg * 32, (void*)&FA[((ktg * 8 + mt) * 64) * 8]);
    }
    __syncthreads();
    MFMA_FA(8)
    __syncthreads();

    // ---- L1 phase C: agg (k 256..383) ----
    STAGE_CVT(agg)
    __syncthreads();
    MFMA_FA(16)

    // reuse: nw2 -> bw[0..7]
    #pragma unroll
    for (int ktg = 0; ktg < 4; ++ktg) {
        bw[ktg * 2 + 0] = *(const bf16x8*)&nw2p[((ktg * 8 + w * 2 + 0) * 64 + l) * 8];
        bw[ktg * 2 + 1] = *(const bf16x8*)&nw2p[((ktg * 8 + w * 2 + 1) * 64 + l) * 8];
    }

    // ---- epilogue 1: bias + relu -> YN ----
    {
        const float b10 = nb1[col0], b11 = nb1[col1];
        #pragma unroll
        for (int mt = 0; mt < 8; ++mt)
            #pragma unroll
            for (int j = 0; j < 4; ++j) {
                const int row = mt * 16 + hi4 * 4 + j;
                float v0 = fmaxf(acc[mt][0][j] + b10, 0.0f);
                float v1 = fmaxf(acc[mt][1][j] + b11, 0.0f);
                YN[row * 136 + col0] = f2b(v0);
                YN[row * 136 + col1] = f2b(v1);
                acc[mt][0][j] = 0.0f; acc[mt][1][j] = 0.0f;
            }
    }
    __syncthreads();

    MFMA_YN(0)         // L2: o = y @ nw2

    // ---- final epilogue: h residual + bias -> out ----
    {
        const float b20 = nb2[col0], b21 = nb2[col1];
        #pragma unroll
        for (int mt = 0; mt < 8; ++mt)
            #pragma unroll
            for (int j = 0; j < 4; ++j) {
                const int rowg = n0 + mt * 16 + hi4 * 4 + j;
                if (rowg < NN) {
                    const size_t rb = (size_t)b * NN + rowg;
                    out[rb * 131 + col0] = h[rb * HH + col0] + acc[mt][0][j] + b20;
                    out[rb * 131 + col1] = h[rb * HH + col1] + acc[mt][1][j] + b21;
                }
            }
    }
}

extern "C" void kernel_launch(void* const* d_in, const int* in_sizes, int n_in,
                              void* d_out, int out_size, void* d_ws, size_t ws_size,
                              hipStream_t stream)
{
    const float* h      = (const float*)d_in[0];
    const float* coord  = (const float*)d_in[1];
    const float* others = (const float*)d_in[2];
    const int*   eidx   = (const int*)d_in[3];
    const float* w1  = (const float*)d_in[4];
    const float* b1  = (const float*)d_in[5];
    const float* w2  = (const float*)d_in[6];
    const float* b2  = (const float*)d_in[7];
    const float* nw1 = (const float*)d_in[8];
    const float* nb1 = (const float*)d_in[9];
    const float* nw2 = (const float*)d_in[10];
    const float* nb2 = (const float*)d_in[11];
    const float* cw1 = (const float*)d_in[12];
    const float* cb1 = (const float*)d_in[13];
    const float* cw2 = (const float*)d_in[14];
    float* out = (float*)d_out;

    // ws layout — ~31.6 MB total (round-3 proven scale)
    float* agg  = (float*)d_ws;                       // 5,120,000 f32
    float* aggt = agg + (size_t)BN * NN * HH;         // 120,000 f32
    float* cnt  = aggt + (size_t)BN * NN * 3;         // 20,000 f32
    ushort_t* hbf  = (ushort_t*)(cnt + NN);           // 5,120,000 bf16
    ushort_t* w1p  = hbf + (size_t)BN * NN * HH;      // 32768
    ushort_t* w2p  = w1p + 32768;                     // 16384
    ushort_t* cw1p = w2p + 16384;                     // 16384
    ushort_t* nw1p = cw1p + 16384;                    // 49152 (K=384)
    ushort_t* nw2p = nw1p + 49152;                    // 16384

    const size_t zero_bytes =
        ((size_t)BN * NN * HH + (size_t)BN * NN * 3 + NN) * sizeof(float);
    hipMemsetAsync(d_ws, 0, zero_bytes, stream);

    const int n4 = (BN * NN * HH) / 4;
    cvt_h_kernel<<<n4 / 256, 256, 0, stream>>>((const float4*)h, (uint2*)hbf, n4);
    pack_w_kernel<<<16, 256, 0, stream>>>(w1, w1p, 256);
    pack_w_kernel<<<8, 256, 0, stream>>>(w2, w2p, 128);
    pack_w_kernel<<<8, 256, 0, stream>>>(cw1, cw1p, 128);
    pack_w_kernel<<<24, 256, 0, stream>>>(nw1, nw1p, 384);
    pack_w_kernel<<<8, 256, 0, stream>>>(nw2, nw2p, 128);

    dim3 eg(NE / 128, BN);
    edge_kernel<<<eg, 256, 0, stream>>>(hbf, coord, eidx, w1p, w2p, cw1p,
                                        w1, b1, b2, cb1, cw2, agg, aggt, cnt);

    dim3 ng((NN + 127) / 128, BN);
    node_kernel<<<ng, 256, 0, stream>>>(hbf, h, coord, others, agg,
                                        nw1p, nw2p, nb1, nb2, aggt, cnt, out);
}

// Round 5
// 586.115 us; speedup vs baseline: 5.7526x; 1.0947x over previous
//
#include <hip/hip_runtime.h>
#include <cstddef>

#define BN 2
#define NN 20000
#define NE 400000
#define HH 128

typedef __attribute__((ext_vector_type(8))) short bf16x8;
typedef __attribute__((ext_vector_type(4))) float f32x4;
typedef unsigned short ushort_t;

__device__ __forceinline__ unsigned short f2b(float f) {
    unsigned u = __float_as_uint(f);
    unsigned r = (u + 0x7FFFu + ((u >> 16) & 1u)) >> 16;
    return (unsigned short)r;
}
__device__ __forceinline__ float b2f(ushort_t v) {
    return __uint_as_float(((unsigned)v) << 16);
}

__device__ __forceinline__ void gll16(const void* g, void* l) {
    __builtin_amdgcn_global_load_lds(
        (const __attribute__((address_space(1))) unsigned int*)g,
        (__attribute__((address_space(3))) unsigned int*)l,
        16, 0, 0);
}

// ---------------------------------------------------------------------------
// prep: h (fp32) -> bf16
// ---------------------------------------------------------------------------
__global__ void cvt_h_kernel(const float4* __restrict__ src, uint2* __restrict__ dst, int n4) {
    int i = blockIdx.x * 256 + threadIdx.x;
    if (i >= n4) return;
    float4 v = src[i];
    uint2 o;
    o.x = (unsigned)f2b(v.x) | ((unsigned)f2b(v.y) << 16);
    o.y = (unsigned)f2b(v.z) | ((unsigned)f2b(v.w) << 16);
    dst[i] = o;
}

// ---------------------------------------------------------------------------
// prep: pack W[K][128] fp32 -> fragment-order bf16 (same bijection as A path)
// ---------------------------------------------------------------------------
__global__ void pack_w_kernel(const float* __restrict__ W, ushort_t* __restrict__ dst, int K) {
    int slot = blockIdx.x * 256 + threadIdx.x;
    int total = (K >> 6) * 1024;
    if (slot >= total) return;
    int l = slot & 63, nt = (slot >> 6) & 7, kt2 = (slot >> 9) & 1, c = slot >> 10;
    int col = nt * 16 + (l & 15);
    int k0 = c * 64 + kt2 * 32 + ((l >> 4) * 8);
    unsigned out[4];
    #pragma unroll
    for (int p = 0; p < 4; ++p) {
        unsigned lo = f2b(W[(size_t)(k0 + 2 * p) * HH + col]);
        unsigned hi = f2b(W[(size_t)(k0 + 2 * p + 1) * HH + col]);
        out[p] = lo | (hi << 16);
    }
    uint4* d = (uint4*)&dst[(size_t)slot * 8];
    *d = make_uint4(out[0], out[1], out[2], out[3]);
}

// ---------------------------------------------------------------------------
// counting sort by row: hist -> scan (rowptr/cursor + cnt float) -> scatter
// ---------------------------------------------------------------------------
__global__ void hist_kernel(const int* __restrict__ eidx, int* __restrict__ histI) {
    int e = blockIdx.x * 256 + threadIdx.x;
    if (e >= NE) return;
    atomicAdd(&histI[eidx[e]], 1);
}

__global__ void scan_kernel(const int* __restrict__ histI, int* __restrict__ cursor,
                            float* __restrict__ cnt) {
    __shared__ int part[256];
    const int t = threadIdx.x;
    const int chunk = (NN + 255) / 256;
    const int lo = t * chunk, hi = min(lo + chunk, NN);
    int s = 0;
    for (int i = lo; i < hi; ++i) s += histI[i];
    part[t] = s;
    __syncthreads();
    for (int d = 1; d < 256; d <<= 1) {
        int v = (t >= d) ? part[t - d] : 0;
        __syncthreads();
        part[t] += v;
        __syncthreads();
    }
    int run = part[t] - s;   // exclusive prefix
    for (int i = lo; i < hi; ++i) {
        cursor[i] = run;
        int hv = histI[i];
        cnt[i] = (float)hv;
        run += hv;
    }
}

__global__ void scatter_kernel(const int* __restrict__ eidx, int* __restrict__ cursor,
                               int* __restrict__ perm) {
    int e = blockIdx.x * 256 + threadIdx.x;
    if (e >= NE) return;
    int p = atomicAdd(&cursor[eidx[e]], 1);
    perm[p] = e;
}

// ===========================================================================
// Edge kernel: 128 sorted edges/block, 4 waves, weights in VGPRs, fp32 accum.
// agg via per-(run,col) segment atomics instead of per-(edge,col).
// ===========================================================================
#define MFMA_FA(BB)                                                               \
    _Pragma("unroll")                                                             \
    for (int ktg = 0; ktg < 4; ++ktg) {                                           \
        _Pragma("unroll")                                                         \
        for (int mt = 0; mt < 8; ++mt) {                                          \
            bf16x8 a = *(const bf16x8*)&FA[((ktg * 8 + mt) * 64 + l) * 8];        \
            acc[mt][0] = __builtin_amdgcn_mfma_f32_16x16x32_bf16(                 \
                a, bw[(BB) + ktg * 2 + 0], acc[mt][0], 0, 0, 0);                  \
            acc[mt][1] = __builtin_amdgcn_mfma_f32_16x16x32_bf16(                 \
                a, bw[(BB) + ktg * 2 + 1], acc[mt][1], 0, 0, 0);                  \
        }                                                                         \
    }

#define MFMA_YN(BB)                                                               \
    _Pragma("unroll")                                                             \
    for (int ktg = 0; ktg < 4; ++ktg) {                                           \
        _Pragma("unroll")                                                         \
        for (int mt = 0; mt < 8; ++mt) {                                          \
            const int row_ = mt * 16 + lo16;                                      \
            bf16x8 a = *(const bf16x8*)&YN[row_ * 136 + ktg * 32 + hi4 * 8];      \
            acc[mt][0] = __builtin_amdgcn_mfma_f32_16x16x32_bf16(                 \
                a, bw[(BB) + ktg * 2 + 0], acc[mt][0], 0, 0, 0);                  \
            acc[mt][1] = __builtin_amdgcn_mfma_f32_16x16x32_bf16(                 \
                a, bw[(BB) + ktg * 2 + 1], acc[mt][1], 0, 0, 0);                  \
        }                                                                         \
    }

__global__ __launch_bounds__(256, 2)
void edge_kernel(const ushort_t* __restrict__ hbf, const float* __restrict__ coord,
                 const int* __restrict__ eidx, const int* __restrict__ perm,
                 const ushort_t* __restrict__ w1p, const ushort_t* __restrict__ w2p,
                 const ushort_t* __restrict__ cw1p,
                 const float* __restrict__ w1, const float* __restrict__ b1,
                 const float* __restrict__ b2, const float* __restrict__ cb1,
                 const float* __restrict__ cw2,
                 float* __restrict__ agg, float* __restrict__ aggt)
{
    __shared__ ushort_t FA[4 * 8 * 64 * 8];   // 32 KB  [ktg][mt][lane][8]
    __shared__ ushort_t YN[128 * 136];        // 34.8 KB natural [row][col]
    __shared__ int Rw[129], Cw[128];
    __shared__ float CD3[128 * 3];
    __shared__ float Rad[128];
    __shared__ float GT[128];

    const int t = threadIdx.x;
    const int l = t & 63;
    const int w = t >> 6;
    const int b = blockIdx.y;
    const int e0 = blockIdx.x * 128;

    const int lo16 = l & 15;
    const int hi4 = l >> 4;
    const int col0 = w * 32 + lo16;
    const int col1 = col0 + 16;

    // w1 B-fragments -> 64 VGPRs
    bf16x8 bw[16];
    #pragma unroll
    for (int ktg = 0; ktg < 8; ++ktg) {
        bw[ktg * 2 + 0] = *(const bf16x8*)&w1p[((ktg * 8 + w * 2 + 0) * 64 + l) * 8];
        bw[ktg * 2 + 1] = *(const bf16x8*)&w1p[((ktg * 8 + w * 2 + 1) * 64 + l) * 8];
    }

    if (t < 128) {
        const int eid = perm[e0 + t];
        int r = eidx[eid], c = eidx[NE + eid];
        Rw[t] = r; Cw[t] = c; GT[t] = 0.0f;
        if (t == 0) Rw[128] = -1;
        const float* cr = coord + ((size_t)b * NN + r) * 3;
        const float* cc = coord + ((size_t)b * NN + c) * 3;
        float d0 = cr[0] - cc[0], d1 = cr[1] - cc[1], d2 = cr[2] - cc[2];
        CD3[t * 3] = d0; CD3[t * 3 + 1] = d1; CD3[t * 3 + 2] = d2;
        Rad[t] = d0 * d0 + d1 * d1 + d2 * d2;
    }

    f32x4 acc[8][2];
    #pragma unroll
    for (int mt = 0; mt < 8; ++mt) { acc[mt][0] = (f32x4)0.0f; acc[mt][1] = (f32x4)0.0f; }

    __syncthreads();   // Rw/Cw visible

    // ---- stage A row-half (K=128) ----
    #pragma unroll
    for (int i = 0; i < 2; ++i) {
        const int mt = w * 2 + i;
        const ushort_t* hb = hbf + ((size_t)b * NN + Rw[mt * 16 + lo16]) * HH + hi4 * 8;
        #pragma unroll
        for (int ktg = 0; ktg < 4; ++ktg)
            gll16(hb + ktg * 32, (void*)&FA[((ktg * 8 + mt) * 64) * 8]);
    }
    __syncthreads();

    MFMA_FA(0)         // L1, k 0..127
    __syncthreads();

    // ---- stage A col-half ----
    #pragma unroll
    for (int i = 0; i < 2; ++i) {
        const int mt = w * 2 + i;
        const ushort_t* hb = hbf + ((size_t)b * NN + Cw[mt * 16 + lo16]) * HH + hi4 * 8;
        #pragma unroll
        for (int ktg = 0; ktg < 4; ++ktg)
            gll16(hb + ktg * 32, (void*)&FA[((ktg * 8 + mt) * 64) * 8]);
    }
    __syncthreads();

    MFMA_FA(8)         // L1, k 128..255

    // reuse B regs: w2 -> bw[0..7], cw1 -> bw[8..15]
    #pragma unroll
    for (int ktg = 0; ktg < 4; ++ktg) {
        bw[ktg * 2 + 0] = *(const bf16x8*)&w2p[((ktg * 8 + w * 2 + 0) * 64 + l) * 8];
        bw[ktg * 2 + 1] = *(const bf16x8*)&w2p[((ktg * 8 + w * 2 + 1) * 64 + l) * 8];
        bw[8 + ktg * 2 + 0] = *(const bf16x8*)&cw1p[((ktg * 8 + w * 2 + 0) * 64 + l) * 8];
        bw[8 + ktg * 2 + 1] = *(const bf16x8*)&cw1p[((ktg * 8 + w * 2 + 1) * 64 + l) * 8];
    }

    // ---- epilogue 1: radial + bias + relu -> YN ----
    {
        const float w1r0 = w1[256 * HH + col0];
        const float w1r1 = w1[256 * HH + col1];
        const float b10 = b1[col0], b11 = b1[col1];
        #pragma unroll
        for (int mt = 0; mt < 8; ++mt)
            #pragma unroll
            for (int j = 0; j < 4; ++j) {
                const int row = mt * 16 + hi4 * 4 + j;
                const float r = Rad[row];
                float v0 = fmaxf(acc[mt][0][j] + r * w1r0 + b10, 0.0f);
                float v1 = fmaxf(acc[mt][1][j] + r * w1r1 + b11, 0.0f);
                YN[row * 136 + col0] = f2b(v0);
                YN[row * 136 + col1] = f2b(v1);
                acc[mt][0][j] = 0.0f; acc[mt][1][j] = 0.0f;
            }
    }
    __syncthreads();

    MFMA_YN(0)         // L2: feat = y1 @ w2
    __syncthreads();

    // ---- feat epilogue: relu -> YN only (no atomics here) ----
    {
        const float b20 = b2[col0], b21 = b2[col1];
        #pragma unroll
        for (int mt = 0; mt < 8; ++mt)
            #pragma unroll
            for (int j = 0; j < 4; ++j) {
                const int row = mt * 16 + hi4 * 4 + j;
                float v0 = fmaxf(acc[mt][0][j] + b20, 0.0f);
                float v1 = fmaxf(acc[mt][1][j] + b21, 0.0f);
                YN[row * 136 + col0] = f2b(v0);
                YN[row * 136 + col1] = f2b(v1);
                acc[mt][0][j] = 0.0f; acc[mt][1][j] = 0.0f;
            }
    }
    __syncthreads();   // YN (feat) complete for all waves

    MFMA_YN(8)         // L3: g1 = feat @ cw1

    // ---- agg segment scan: one atomic per (row-run, col) ----
    // 4 waves: wave w covers rows [ (w>>1)*64, +64 ), cols (t&127)
    {
        const int colc = t & 127;
        const int half = t >> 7;
        const int r0 = half * 64;
        float s = 0.0f;
        for (int r = r0; r < r0 + 64; ++r) {
            s += b2f(YN[r * 136 + colc]);
            // wave-uniform flush decision (Rw[128] = -1 guards r==127)
            if (r == r0 + 63 || Rw[r] != Rw[r + 1]) {
                atomicAdd(&agg[((size_t)b * NN + Rw[r]) * HH + colc], s);
                s = 0.0f;
            }
        }
    }

    // ---- gate epilogue ----
    {
        const float cbA = cb1[col0], cbB = cb1[col1];
        const float cwA = cw2[col0], cwB = cw2[col1];
        #pragma unroll
        for (int mt = 0; mt < 8; ++mt)
            #pragma unroll
            for (int j = 0; j < 4; ++j) {
                float g = fmaxf(acc[mt][0][j] + cbA, 0.0f) * cwA
                        + fmaxf(acc[mt][1][j] + cbB, 0.0f) * cwB;
                g += __shfl_xor(g, 1);
                g += __shfl_xor(g, 2);
                g += __shfl_xor(g, 4);
                g += __shfl_xor(g, 8);
                if (lo16 == 0)
                    atomicAdd(&GT[mt * 16 + hi4 * 4 + j], g);
            }
    }
    __syncthreads();

    // ---- aggt run-reduce: run-head sums its run, 3 atomics per run ----
    if (t < 128) {
        const bool head = (t == 0) || (Rw[t] != Rw[t - 1]);
        if (head) {
            float s0 = 0.0f, s1 = 0.0f, s2 = 0.0f;
            int r = t;
            const int myrow = Rw[t];
            while (r < 128 && Rw[r] == myrow) {
                const float g = GT[r];
                s0 += CD3[r * 3 + 0] * g;
                s1 += CD3[r * 3 + 1] * g;
                s2 += CD3[r * 3 + 2] * g;
                ++r;
            }
            const size_t base = ((size_t)b * NN + myrow) * 3;
            atomicAdd(&aggt[base + 0], s0);
            atomicAdd(&aggt[base + 1], s1);
            atomicAdd(&aggt[base + 2], s2);
        }
    }
}

// ===========================================================================
// Node kernel: 128 nodes/block, MFMA, nw1 (K=384) in 96 VGPRs. (unchanged)
// ===========================================================================
__global__ __launch_bounds__(256, 2)
void node_kernel(const ushort_t* __restrict__ hbf, const float* __restrict__ h,
                 const float* __restrict__ coord, const float* __restrict__ others,
                 const float* __restrict__ agg,
                 const ushort_t* __restrict__ nw1p, const ushort_t* __restrict__ nw2p,
                 const float* __restrict__ nb1, const float* __restrict__ nb2,
                 const float* __restrict__ aggt, const float* __restrict__ cnt,
                 float* __restrict__ out)
{
    __shared__ ushort_t FA[4 * 8 * 64 * 8];
    __shared__ ushort_t YN[128 * 136];

    const int t = threadIdx.x;
    const int l = t & 63;
    const int w = t >> 6;
    const int b = blockIdx.y;
    const int n0 = blockIdx.x * 128;

    const int lo16 = l & 15;
    const int hi4 = l >> 4;
    const int col0 = w * 32 + lo16;
    const int col1 = col0 + 16;

    bf16x8 bw[24];
    #pragma unroll
    for (int ktg = 0; ktg < 12; ++ktg) {
        bw[ktg * 2 + 0] = *(const bf16x8*)&nw1p[((ktg * 8 + w * 2 + 0) * 64 + l) * 8];
        bw[ktg * 2 + 1] = *(const bf16x8*)&nw1p[((ktg * 8 + w * 2 + 1) * 64 + l) * 8];
    }

    if (t < 128) {
        const int n = n0 + t;
        if (n < NN) {
            const float rinv = 1.0f / fmaxf(cnt[n], 1.0f);
            const float* cp = coord + ((size_t)b * NN + n) * 3;
            const float* ap = aggt + ((size_t)b * NN + n) * 3;
            float* op = out + ((size_t)b * NN + n) * 131 + HH;
            op[0] = cp[0] + ap[0] * rinv;
            op[1] = cp[1] + ap[1] * rinv;
            op[2] = cp[2] + ap[2] * rinv;
        }
    }

    f32x4 acc[8][2];
    #pragma unroll
    for (int mt = 0; mt < 8; ++mt) { acc[mt][0] = (f32x4)0.0f; acc[mt][1] = (f32x4)0.0f; }

    #define STAGE_CVT(SRC)                                                        \
        _Pragma("unroll")                                                         \
        for (int i = 0; i < 2; ++i) {                                             \
            const int mt = w * 2 + i;                                             \
            const int row = min(n0 + mt * 16 + lo16, NN - 1);                     \
            const float* p = (SRC) + ((size_t)b * NN + row) * HH + hi4 * 8;       \
            _Pragma("unroll")                                                     \
            for (int ktg = 0; ktg < 4; ++ktg) {                                   \
                float4 fa = *(const float4*)(p + ktg * 32);                       \
                float4 fb = *(const float4*)(p + ktg * 32 + 4);                   \
                uint4 u;                                                          \
                u.x = (unsigned)f2b(fa.x) | ((unsigned)f2b(fa.y) << 16);          \
                u.y = (unsigned)f2b(fa.z) | ((unsigned)f2b(fa.w) << 16);          \
                u.z = (unsigned)f2b(fb.x) | ((unsigned)f2b(fb.y) << 16);          \
                u.w = (unsigned)f2b(fb.z) | ((unsigned)f2b(fb.w) << 16);          \
                *(uint4*)&FA[((ktg * 8 + mt) * 64 + l) * 8] = u;                  \
            }                                                                     \
        }

    STAGE_CVT(others)
    __syncthreads();
    MFMA_FA(0)
    __syncthreads();

    #pragma unroll
    for (int i = 0; i < 2; ++i) {
        const int mt = w * 2 + i;
        const int row = min(n0 + mt * 16 + lo16, NN - 1);
        const ushort_t* hb = hbf + ((size_t)b * NN + row) * HH + hi4 * 8;
        #pragma unroll
        for (int ktg = 0; ktg < 4; ++ktg)
            gll16(hb + ktg * 32, (void*)&FA[((ktg * 8 + mt) * 64) * 8]);
    }
    __syncthreads();
    MFMA_FA(8)
    __syncthreads();

    STAGE_CVT(agg)
    __syncthreads();
    MFMA_FA(16)

    #pragma unroll
    for (int ktg = 0; ktg < 4; ++ktg) {
        bw[ktg * 2 + 0] = *(const bf16x8*)&nw2p[((ktg * 8 + w * 2 + 0) * 64 + l) * 8];
        bw[ktg * 2 + 1] = *(const bf16x8*)&nw2p[((ktg * 8 + w * 2 + 1) * 64 + l) * 8];
    }

    {
        const float b10 = nb1[col0], b11 = nb1[col1];
        #pragma unroll
        for (int mt = 0; mt < 8; ++mt)
            #pragma unroll
            for (int j = 0; j < 4; ++j) {
                const int row = mt * 16 + hi4 * 4 + j;
                float v0 = fmaxf(acc[mt][0][j] + b10, 0.0f);
                float v1 = fmaxf(acc[mt][1][j] + b11, 0.0f);
                YN[row * 136 + col0] = f2b(v0);
                YN[row * 136 + col1] = f2b(v1);
                acc[mt][0][j] = 0.0f; acc[mt][1][j] = 0.0f;
            }
    }
    __syncthreads();

    MFMA_YN(0)

    {
        const float b20 = nb2[col0], b21 = nb2[col1];
        #pragma unroll
        for (int mt = 0; mt < 8; ++mt)
            #pragma unroll
            for (int j = 0; j < 4; ++j) {
                const int rowg = n0 + mt * 16 + hi4 * 4 + j;
                if (rowg < NN) {
                    const size_t rb = (size_t)b * NN + rowg;
                    out[rb * 131 + col0] = h[rb * HH + col0] + acc[mt][0][j] + b20;
                    out[rb * 131 + col1] = h[rb * HH + col1] + acc[mt][1][j] + b21;
                }
            }
    }
}

extern "C" void kernel_launch(void* const* d_in, const int* in_sizes, int n_in,
                              void* d_out, int out_size, void* d_ws, size_t ws_size,
                              hipStream_t stream)
{
    const float* h      = (const float*)d_in[0];
    const float* coord  = (const float*)d_in[1];
    const float* others = (const float*)d_in[2];
    const int*   eidx   = (const int*)d_in[3];
    const float* w1  = (const float*)d_in[4];
    const float* b1  = (const float*)d_in[5];
    const float* w2  = (const float*)d_in[6];
    const float* b2  = (const float*)d_in[7];
    const float* nw1 = (const float*)d_in[8];
    const float* nb1 = (const float*)d_in[9];
    const float* nw2 = (const float*)d_in[10];
    const float* nb2 = (const float*)d_in[11];
    const float* cw1 = (const float*)d_in[12];
    const float* cb1 = (const float*)d_in[13];
    const float* cw2 = (const float*)d_in[14];
    float* out = (float*)d_out;

    // ws layout — ~33.3 MB total
    float* agg   = (float*)d_ws;                      // 5,120,000 f (zeroed)
    float* aggt  = agg + (size_t)BN * NN * HH;        // 120,000 f  (zeroed)
    int*   histI = (int*)(aggt + (size_t)BN * NN * 3);// 20,000 i   (zeroed)
    float* cnt   = (float*)(histI + NN);              // 20,000 f   (scan-written)
    int*   cursor= (int*)(cnt + NN);                  // 20,000 i   (scan-written)
    int*   perm  = cursor + NN;                       // 400,000 i  (scatter-written)
    ushort_t* hbf  = (ushort_t*)(perm + NE);          // 5,120,000 bf16
    ushort_t* w1p  = hbf + (size_t)BN * NN * HH;      // 32768
    ushort_t* w2p  = w1p + 32768;                     // 16384
    ushort_t* cw1p = w2p + 16384;                     // 16384
    ushort_t* nw1p = cw1p + 16384;                    // 49152
    ushort_t* nw2p = nw1p + 49152;                    // 16384

    const size_t zero_bytes =
        ((size_t)BN * NN * HH + (size_t)BN * NN * 3 + NN) * sizeof(float);
    hipMemsetAsync(d_ws, 0, zero_bytes, stream);   // agg + aggt + histI

    const int n4 = (BN * NN * HH) / 4;
    cvt_h_kernel<<<n4 / 256, 256, 0, stream>>>((const float4*)h, (uint2*)hbf, n4);
    pack_w_kernel<<<16, 256, 0, stream>>>(w1, w1p, 256);
    pack_w_kernel<<<8, 256, 0, stream>>>(w2, w2p, 128);
    pack_w_kernel<<<8, 256, 0, stream>>>(cw1, cw1p, 128);
    pack_w_kernel<<<24, 256, 0, stream>>>(nw1, nw1p, 384);
    pack_w_kernel<<<8, 256, 0, stream>>>(nw2, nw2p, 128);

    hist_kernel<<<(NE + 255) / 256, 256, 0, stream>>>(eidx, histI);
    scan_kernel<<<1, 256, 0, stream>>>(histI, cursor, cnt);
    scatter_kernel<<<(NE + 255) / 256, 256, 0, stream>>>(eidx, cursor, perm);

    dim3 eg(NE / 128, BN);
    edge_kernel<<<eg, 256, 0, stream>>>(hbf, coord, eidx, perm, w1p, w2p, cw1p,
                                        w1, b1, b2, cb1, cw2, agg, aggt);

    dim3 ng((NN + 127) / 128, BN);
    node_kernel<<<ng, 256, 0, stream>>>(hbf, h, coord, others, agg,
                                        nw1p, nw2p, nb1, nb2, aggt, cnt, out);
}

// Round 6
// 489.512 us; speedup vs baseline: 6.8878x; 1.1973x over previous
//
#include <hip/hip_runtime.h>
#include <cstddef>

#define BN 2
#define NN 20000
#define NE 400000
#define HH 128

typedef __attribute__((ext_vector_type(8))) short bf16x8;
typedef __attribute__((ext_vector_type(4))) float f32x4;
typedef unsigned short ushort_t;

__device__ __forceinline__ unsigned short f2b(float f) {
    unsigned u = __float_as_uint(f);
    unsigned r = (u + 0x7FFFu + ((u >> 16) & 1u)) >> 16;
    return (unsigned short)r;
}
__device__ __forceinline__ float b2f(ushort_t v) {
    return __uint_as_float(((unsigned)v) << 16);
}

__device__ __forceinline__ void gll16(const void* g, void* l) {
    __builtin_amdgcn_global_load_lds(
        (const __attribute__((address_space(1))) unsigned int*)g,
        (__attribute__((address_space(3))) unsigned int*)l,
        16, 0, 0);
}

// ---------------------------------------------------------------------------
// prep: h (fp32) -> bf16
// ---------------------------------------------------------------------------
__global__ void cvt_h_kernel(const float4* __restrict__ src, uint2* __restrict__ dst, int n4) {
    int i = blockIdx.x * 256 + threadIdx.x;
    if (i >= n4) return;
    float4 v = src[i];
    uint2 o;
    o.x = (unsigned)f2b(v.x) | ((unsigned)f2b(v.y) << 16);
    o.y = (unsigned)f2b(v.z) | ((unsigned)f2b(v.w) << 16);
    dst[i] = o;
}

// ---------------------------------------------------------------------------
// prep: pack W[K][128] fp32 -> fragment-order bf16 (same bijection as A path)
// ---------------------------------------------------------------------------
__global__ void pack_w_kernel(const float* __restrict__ W, ushort_t* __restrict__ dst, int K) {
    int slot = blockIdx.x * 256 + threadIdx.x;
    int total = (K >> 6) * 1024;
    if (slot >= total) return;
    int l = slot & 63, nt = (slot >> 6) & 7, kt2 = (slot >> 9) & 1, c = slot >> 10;
    int col = nt * 16 + (l & 15);
    int k0 = c * 64 + kt2 * 32 + ((l >> 4) * 8);
    unsigned out[4];
    #pragma unroll
    for (int p = 0; p < 4; ++p) {
        unsigned lo = f2b(W[(size_t)(k0 + 2 * p) * HH + col]);
        unsigned hi = f2b(W[(size_t)(k0 + 2 * p + 1) * HH + col]);
        out[p] = lo | (hi << 16);
    }
    uint4* d = (uint4*)&dst[(size_t)slot * 8];
    *d = make_uint4(out[0], out[1], out[2], out[3]);
}

// ---------------------------------------------------------------------------
// counting sort by row: hist -> scan -> scatter (materializes rowS/colS)
// ---------------------------------------------------------------------------
__global__ void hist_kernel(const int* __restrict__ eidx, int* __restrict__ histI) {
    int e = blockIdx.x * 256 + threadIdx.x;
    if (e >= NE) return;
    atomicAdd(&histI[eidx[e]], 1);
}

__global__ void scan_kernel(const int* __restrict__ histI, int* __restrict__ cursor,
                            float* __restrict__ cnt) {
    __shared__ int part[256];
    const int t = threadIdx.x;
    const int chunk = (NN + 255) / 256;
    const int lo = t * chunk, hi = min(lo + chunk, NN);
    int s = 0;
    for (int i = lo; i < hi; ++i) s += histI[i];
    part[t] = s;
    __syncthreads();
    for (int d = 1; d < 256; d <<= 1) {
        int v = (t >= d) ? part[t - d] : 0;
        __syncthreads();
        part[t] += v;
        __syncthreads();
    }
    int run = part[t] - s;   // exclusive prefix
    for (int i = lo; i < hi; ++i) {
        cursor[i] = run;
        int hv = histI[i];
        cnt[i] = (float)hv;
        run += hv;
    }
}

__global__ void scatter_kernel(const int* __restrict__ eidx, int* __restrict__ cursor,
                               int* __restrict__ rowS, int* __restrict__ colS) {
    int e = blockIdx.x * 256 + threadIdx.x;
    if (e >= NE) return;
    const int r = eidx[e];
    int p = atomicAdd(&cursor[r], 1);
    rowS[p] = r;
    colS[p] = eidx[NE + e];
}

// ===========================================================================
// Edge kernel: 128 sorted edges/block, 4 waves, weights in VGPRs, fp32 accum.
// FA/YN share one LDS buffer (overlay) -> ~38.5 KB LDS -> 4 blocks/CU.
// ===========================================================================
#define MFMA_FA(BB)                                                               \
    _Pragma("unroll")                                                             \
    for (int ktg = 0; ktg < 4; ++ktg) {                                           \
        _Pragma("unroll")                                                         \
        for (int mt = 0; mt < 8; ++mt) {                                          \
            bf16x8 a = *(const bf16x8*)&FA[((ktg * 8 + mt) * 64 + l) * 8];        \
            acc[mt][0] = __builtin_amdgcn_mfma_f32_16x16x32_bf16(                 \
                a, bw[(BB) + ktg * 2 + 0], acc[mt][0], 0, 0, 0);                  \
            acc[mt][1] = __builtin_amdgcn_mfma_f32_16x16x32_bf16(                 \
                a, bw[(BB) + ktg * 2 + 1], acc[mt][1], 0, 0, 0);                  \
        }                                                                         \
    }

#define MFMA_YN(BB)                                                               \
    _Pragma("unroll")                                                             \
    for (int ktg = 0; ktg < 4; ++ktg) {                                           \
        _Pragma("unroll")                                                         \
        for (int mt = 0; mt < 8; ++mt) {                                          \
            const int row_ = mt * 16 + lo16;                                      \
            bf16x8 a = *(const bf16x8*)&YN[row_ * 136 + ktg * 32 + hi4 * 8];      \
            acc[mt][0] = __builtin_amdgcn_mfma_f32_16x16x32_bf16(                 \
                a, bw[(BB) + ktg * 2 + 0], acc[mt][0], 0, 0, 0);                  \
            acc[mt][1] = __builtin_amdgcn_mfma_f32_16x16x32_bf16(                 \
                a, bw[(BB) + ktg * 2 + 1], acc[mt][1], 0, 0, 0);                  \
        }                                                                         \
    }

__global__ __launch_bounds__(256, 4)
void edge_kernel(const ushort_t* __restrict__ hbf, const float* __restrict__ coord,
                 const int* __restrict__ rowS, const int* __restrict__ colS,
                 const ushort_t* __restrict__ w1p, const ushort_t* __restrict__ w2p,
                 const ushort_t* __restrict__ cw1p,
                 const float* __restrict__ w1, const float* __restrict__ b1,
                 const float* __restrict__ b2, const float* __restrict__ cb1,
                 const float* __restrict__ cw2,
                 float* __restrict__ agg, float* __restrict__ aggt)
{
    __shared__ ushort_t SH[128 * 136];        // 34.8 KB — FA (16384) / YN overlay
    __shared__ int Rw[129], Cw[128];
    __shared__ float CD3[128 * 3];
    __shared__ float Rad[128];
    __shared__ float GT[128];

    ushort_t* const FA = SH;
    ushort_t* const YN = SH;

    const int t = threadIdx.x;
    const int l = t & 63;
    const int w = t >> 6;
    const int b = blockIdx.y;
    const int e0 = blockIdx.x * 128;

    const int lo16 = l & 15;
    const int hi4 = l >> 4;
    const int col0 = w * 32 + lo16;
    const int col1 = col0 + 16;

    // w1 B-fragments -> 64 VGPRs
    bf16x8 bw[16];
    #pragma unroll
    for (int ktg = 0; ktg < 8; ++ktg) {
        bw[ktg * 2 + 0] = *(const bf16x8*)&w1p[((ktg * 8 + w * 2 + 0) * 64 + l) * 8];
        bw[ktg * 2 + 1] = *(const bf16x8*)&w1p[((ktg * 8 + w * 2 + 1) * 64 + l) * 8];
    }

    if (t < 128) {
        int r = rowS[e0 + t], c = colS[e0 + t];
        Rw[t] = r; Cw[t] = c; GT[t] = 0.0f;
        if (t == 0) Rw[128] = -1;
        const float* cr = coord + ((size_t)b * NN + r) * 3;
        const float* cc = coord + ((size_t)b * NN + c) * 3;
        float d0 = cr[0] - cc[0], d1 = cr[1] - cc[1], d2 = cr[2] - cc[2];
        CD3[t * 3] = d0; CD3[t * 3 + 1] = d1; CD3[t * 3 + 2] = d2;
        Rad[t] = d0 * d0 + d1 * d1 + d2 * d2;
    }

    f32x4 acc[8][2];
    #pragma unroll
    for (int mt = 0; mt < 8; ++mt) { acc[mt][0] = (f32x4)0.0f; acc[mt][1] = (f32x4)0.0f; }

    __syncthreads();   // Rw/Cw visible

    // ---- stage A row-half (K=128) ----
    #pragma unroll
    for (int i = 0; i < 2; ++i) {
        const int mt = w * 2 + i;
        const ushort_t* hb = hbf + ((size_t)b * NN + Rw[mt * 16 + lo16]) * HH + hi4 * 8;
        #pragma unroll
        for (int ktg = 0; ktg < 4; ++ktg)
            gll16(hb + ktg * 32, (void*)&FA[((ktg * 8 + mt) * 64) * 8]);
    }
    __syncthreads();

    MFMA_FA(0)         // L1, k 0..127
    __syncthreads();

    // ---- stage A col-half ----
    #pragma unroll
    for (int i = 0; i < 2; ++i) {
        const int mt = w * 2 + i;
        const ushort_t* hb = hbf + ((size_t)b * NN + Cw[mt * 16 + lo16]) * HH + hi4 * 8;
        #pragma unroll
        for (int ktg = 0; ktg < 4; ++ktg)
            gll16(hb + ktg * 32, (void*)&FA[((ktg * 8 + mt) * 64) * 8]);
    }
    __syncthreads();

    MFMA_FA(8)         // L1, k 128..255

    // reuse B regs: w2 -> bw[0..7], cw1 -> bw[8..15] (global, overlaps barrier)
    #pragma unroll
    for (int ktg = 0; ktg < 4; ++ktg) {
        bw[ktg * 2 + 0] = *(const bf16x8*)&w2p[((ktg * 8 + w * 2 + 0) * 64 + l) * 8];
        bw[ktg * 2 + 1] = *(const bf16x8*)&w2p[((ktg * 8 + w * 2 + 1) * 64 + l) * 8];
        bw[8 + ktg * 2 + 0] = *(const bf16x8*)&cw1p[((ktg * 8 + w * 2 + 0) * 64 + l) * 8];
        bw[8 + ktg * 2 + 1] = *(const bf16x8*)&cw1p[((ktg * 8 + w * 2 + 1) * 64 + l) * 8];
    }

    __syncthreads();   // WAR: all FA readers done before YN overwrite (overlay)

    // ---- epilogue 1: radial + bias + relu -> YN ----
    {
        const float w1r0 = w1[256 * HH + col0];
        const float w1r1 = w1[256 * HH + col1];
        const float b10 = b1[col0], b11 = b1[col1];
        #pragma unroll
        for (int mt = 0; mt < 8; ++mt)
            #pragma unroll
            for (int j = 0; j < 4; ++j) {
                const int row = mt * 16 + hi4 * 4 + j;
                const float r = Rad[row];
                float v0 = fmaxf(acc[mt][0][j] + r * w1r0 + b10, 0.0f);
                float v1 = fmaxf(acc[mt][1][j] + r * w1r1 + b11, 0.0f);
                YN[row * 136 + col0] = f2b(v0);
                YN[row * 136 + col1] = f2b(v1);
                acc[mt][0][j] = 0.0f; acc[mt][1][j] = 0.0f;
            }
    }
    __syncthreads();

    MFMA_YN(0)         // L2: feat = y1 @ w2
    __syncthreads();

    // ---- feat epilogue: relu -> YN ----
    {
        const float b20 = b2[col0], b21 = b2[col1];
        #pragma unroll
        for (int mt = 0; mt < 8; ++mt)
            #pragma unroll
            for (int j = 0; j < 4; ++j) {
                const int row = mt * 16 + hi4 * 4 + j;
                float v0 = fmaxf(acc[mt][0][j] + b20, 0.0f);
                float v1 = fmaxf(acc[mt][1][j] + b21, 0.0f);
                YN[row * 136 + col0] = f2b(v0);
                YN[row * 136 + col1] = f2b(v1);
                acc[mt][0][j] = 0.0f; acc[mt][1][j] = 0.0f;
            }
    }
    __syncthreads();   // YN (feat) complete for all waves

    MFMA_YN(8)         // L3: g1 = feat @ cw1

    // ---- agg segment scan: one atomic per (row-run, col) ----
    {
        const int colc = t & 127;
        const int half = t >> 7;
        const int r0 = half * 64;
        float s = 0.0f;
        for (int r = r0; r < r0 + 64; ++r) {
            s += b2f(YN[r * 136 + colc]);
            if (r == r0 + 63 || Rw[r] != Rw[r + 1]) {   // wave-uniform flush
                atomicAdd(&agg[((size_t)b * NN + Rw[r]) * HH + colc], s);
                s = 0.0f;
            }
        }
    }

    // ---- gate epilogue ----
    {
        const float cbA = cb1[col0], cbB = cb1[col1];
        const float cwA = cw2[col0], cwB = cw2[col1];
        #pragma unroll
        for (int mt = 0; mt < 8; ++mt)
            #pragma unroll
            for (int j = 0; j < 4; ++j) {
                float g = fmaxf(acc[mt][0][j] + cbA, 0.0f) * cwA
                        + fmaxf(acc[mt][1][j] + cbB, 0.0f) * cwB;
                g += __shfl_xor(g, 1);
                g += __shfl_xor(g, 2);
                g += __shfl_xor(g, 4);
                g += __shfl_xor(g, 8);
                if (lo16 == 0)
                    atomicAdd(&GT[mt * 16 + hi4 * 4 + j], g);
            }
    }
    __syncthreads();

    // ---- aggt run-reduce: run-head sums its run, 3 atomics per run ----
    if (t < 128) {
        const bool head = (t == 0) || (Rw[t] != Rw[t - 1]);
        if (head) {
            float s0 = 0.0f, s1 = 0.0f, s2 = 0.0f;
            int r = t;
            const int myrow = Rw[t];
            while (r < 128 && Rw[r] == myrow) {
                const float g = GT[r];
                s0 += CD3[r * 3 + 0] * g;
                s1 += CD3[r * 3 + 1] * g;
                s2 += CD3[r * 3 + 2] * g;
                ++r;
            }
            const size_t base = ((size_t)b * NN + myrow) * 3;
            atomicAdd(&aggt[base + 0], s0);
            atomicAdd(&aggt[base + 1], s1);
            atomicAdd(&aggt[base + 2], s2);
        }
    }
}

// ===========================================================================
// Node kernel: 128 nodes/block, MFMA, nw1 (K=384) in 96 VGPRs. FA/YN overlay.
// ===========================================================================
__global__ __launch_bounds__(256, 2)
void node_kernel(const ushort_t* __restrict__ hbf, const float* __restrict__ h,
                 const float* __restrict__ coord, const float* __restrict__ others,
                 const float* __restrict__ agg,
                 const ushort_t* __restrict__ nw1p, const ushort_t* __restrict__ nw2p,
                 const float* __restrict__ nb1, const float* __restrict__ nb2,
                 const float* __restrict__ aggt, const float* __restrict__ cnt,
                 float* __restrict__ out)
{
    __shared__ ushort_t SH[128 * 136];        // FA/YN overlay
    ushort_t* const FA = SH;
    ushort_t* const YN = SH;

    const int t = threadIdx.x;
    const int l = t & 63;
    const int w = t >> 6;
    const int b = blockIdx.y;
    const int n0 = blockIdx.x * 128;

    const int lo16 = l & 15;
    const int hi4 = l >> 4;
    const int col0 = w * 32 + lo16;
    const int col1 = col0 + 16;

    bf16x8 bw[24];
    #pragma unroll
    for (int ktg = 0; ktg < 12; ++ktg) {
        bw[ktg * 2 + 0] = *(const bf16x8*)&nw1p[((ktg * 8 + w * 2 + 0) * 64 + l) * 8];
        bw[ktg * 2 + 1] = *(const bf16x8*)&nw1p[((ktg * 8 + w * 2 + 1) * 64 + l) * 8];
    }

    if (t < 128) {
        const int n = n0 + t;
        if (n < NN) {
            const float rinv = 1.0f / fmaxf(cnt[n], 1.0f);
            const float* cp = coord + ((size_t)b * NN + n) * 3;
            const float* ap = aggt + ((size_t)b * NN + n) * 3;
            float* op = out + ((size_t)b * NN + n) * 131 + HH;
            op[0] = cp[0] + ap[0] * rinv;
            op[1] = cp[1] + ap[1] * rinv;
            op[2] = cp[2] + ap[2] * rinv;
        }
    }

    f32x4 acc[8][2];
    #pragma unroll
    for (int mt = 0; mt < 8; ++mt) { acc[mt][0] = (f32x4)0.0f; acc[mt][1] = (f32x4)0.0f; }

    #define STAGE_CVT(SRC)                                                        \
        _Pragma("unroll")                                                         \
        for (int i = 0; i < 2; ++i) {                                             \
            const int mt = w * 2 + i;                                             \
            const int row = min(n0 + mt * 16 + lo16, NN - 1);                     \
            const float* p = (SRC) + ((size_t)b * NN + row) * HH + hi4 * 8;       \
            _Pragma("unroll")                                                     \
            for (int ktg = 0; ktg < 4; ++ktg) {                                   \
                float4 fa = *(const float4*)(p + ktg * 32);                       \
                float4 fb = *(const float4*)(p + ktg * 32 + 4);                   \
                uint4 u;                                                          \
                u.x = (unsigned)f2b(fa.x) | ((unsigned)f2b(fa.y) << 16);          \
                u.y = (unsigned)f2b(fa.z) | ((unsigned)f2b(fa.w) << 16);          \
                u.z = (unsigned)f2b(fb.x) | ((unsigned)f2b(fb.y) << 16);          \
                u.w = (unsigned)f2b(fb.z) | ((unsigned)f2b(fb.w) << 16);          \
                *(uint4*)&FA[((ktg * 8 + mt) * 64 + l) * 8] = u;                  \
            }                                                                     \
        }

    STAGE_CVT(others)
    __syncthreads();
    MFMA_FA(0)
    __syncthreads();

    #pragma unroll
    for (int i = 0; i < 2; ++i) {
        const int mt = w * 2 + i;
        const int row = min(n0 + mt * 16 + lo16, NN - 1);
        const ushort_t* hb = hbf + ((size_t)b * NN + row) * HH + hi4 * 8;
        #pragma unroll
        for (int ktg = 0; ktg < 4; ++ktg)
            gll16(hb + ktg * 32, (void*)&FA[((ktg * 8 + mt) * 64) * 8]);
    }
    __syncthreads();
    MFMA_FA(8)
    __syncthreads();

    STAGE_CVT(agg)
    __syncthreads();
    MFMA_FA(16)

    #pragma unroll
    for (int ktg = 0; ktg < 4; ++ktg) {
        bw[ktg * 2 + 0] = *(const bf16x8*)&nw2p[((ktg * 8 + w * 2 + 0) * 64 + l) * 8];
        bw[ktg * 2 + 1] = *(const bf16x8*)&nw2p[((ktg * 8 + w * 2 + 1) * 64 + l) * 8];
    }

    __syncthreads();   // WAR: FA readers done before YN overwrite (overlay)

    {
        const float b10 = nb1[col0], b11 = nb1[col1];
        #pragma unroll
        for (int mt = 0; mt < 8; ++mt)
            #pragma unroll
            for (int j = 0; j < 4; ++j) {
                const int row = mt * 16 + hi4 * 4 + j;
                float v0 = fmaxf(acc[mt][0][j] + b10, 0.0f);
                float v1 = fmaxf(acc[mt][1][j] + b11, 0.0f);
                YN[row * 136 + col0] = f2b(v0);
                YN[row * 136 + col1] = f2b(v1);
                acc[mt][0][j] = 0.0f; acc[mt][1][j] = 0.0f;
            }
    }
    __syncthreads();

    MFMA_YN(0)

    {
        const float b20 = nb2[col0], b21 = nb2[col1];
        #pragma unroll
        for (int mt = 0; mt < 8; ++mt)
            #pragma unroll
            for (int j = 0; j < 4; ++j) {
                const int rowg = n0 + mt * 16 + hi4 * 4 + j;
                if (rowg < NN) {
                    const size_t rb = (size_t)b * NN + rowg;
                    out[rb * 131 + col0] = h[rb * HH + col0] + acc[mt][0][j] + b20;
                    out[rb * 131 + col1] = h[rb * HH + col1] + acc[mt][1][j] + b21;
                }
            }
    }
}

extern "C" void kernel_launch(void* const* d_in, const int* in_sizes, int n_in,
                              void* d_out, int out_size, void* d_ws, size_t ws_size,
                              hipStream_t stream)
{
    const float* h      = (const float*)d_in[0];
    const float* coord  = (const float*)d_in[1];
    const float* others = (const float*)d_in[2];
    const int*   eidx   = (const int*)d_in[3];
    const float* w1  = (const float*)d_in[4];
    const float* b1  = (const float*)d_in[5];
    const float* w2  = (const float*)d_in[6];
    const float* b2  = (const float*)d_in[7];
    const float* nw1 = (const float*)d_in[8];
    const float* nb1 = (const float*)d_in[9];
    const float* nw2 = (const float*)d_in[10];
    const float* nb2 = (const float*)d_in[11];
    const float* cw1 = (const float*)d_in[12];
    const float* cb1 = (const float*)d_in[13];
    const float* cw2 = (const float*)d_in[14];
    float* out = (float*)d_out;

    // ws layout — ~35 MB total
    float* agg   = (float*)d_ws;                      // 5,120,000 f (zeroed)
    float* aggt  = agg + (size_t)BN * NN * HH;        // 120,000 f  (zeroed)
    int*   histI = (int*)(aggt + (size_t)BN * NN * 3);// 20,000 i   (zeroed)
    float* cnt   = (float*)(histI + NN);              // 20,000 f   (scan-written)
    int*   cursor= (int*)(cnt + NN);                  // 20,000 i   (scan-written)
    int*   rowS  = cursor + NN;                       // 400,000 i  (scatter-written)
    int*   colS  = rowS + NE;                         // 400,000 i  (scatter-written)
    ushort_t* hbf  = (ushort_t*)(colS + NE);          // 5,120,000 bf16
    ushort_t* w1p  = hbf + (size_t)BN * NN * HH;      // 32768
    ushort_t* w2p  = w1p + 32768;                     // 16384
    ushort_t* cw1p = w2p + 16384;                     // 16384
    ushort_t* nw1p = cw1p + 16384;                    // 49152
    ushort_t* nw2p = nw1p + 49152;                    // 16384

    const size_t zero_bytes =
        ((size_t)BN * NN * HH + (size_t)BN * NN * 3 + NN) * sizeof(float);
    hipMemsetAsync(d_ws, 0, zero_bytes, stream);   // agg + aggt + histI

    const int n4 = (BN * NN * HH) / 4;
    cvt_h_kernel<<<n4 / 256, 256, 0, stream>>>((const float4*)h, (uint2*)hbf, n4);
    pack_w_kernel<<<16, 256, 0, stream>>>(w1, w1p, 256);
    pack_w_kernel<<<8, 256, 0, stream>>>(w2, w2p, 128);
    pack_w_kernel<<<8, 256, 0, stream>>>(cw1, cw1p, 128);
    pack_w_kernel<<<24, 256, 0, stream>>>(nw1, nw1p, 384);
    pack_w_kernel<<<8, 256, 0, stream>>>(nw2, nw2p, 128);

    hist_kernel<<<(NE + 255) / 256, 256, 0, stream>>>(eidx, histI);
    scan_kernel<<<1, 256, 0, stream>>>(histI, cursor, cnt);
    scatter_kernel<<<(NE + 255) / 256, 256, 0, stream>>>(eidx, cursor, rowS, colS);

    dim3 eg(NE / 128, BN);
    edge_kernel<<<eg, 256, 0, stream>>>(hbf, coord, rowS, colS, w1p, w2p, cw1p,
                                        w1, b1, b2, cb1, cw2, agg, aggt);

    dim3 ng((NN + 127) / 128, BN);
    node_kernel<<<ng, 256, 0, stream>>>(hbf, h, coord, others, agg,
                                        nw1p, nw2p, nb1, nb2, aggt, cnt, out);
}